// Round 1
// baseline (74.180 us; speedup 1.0000x reference)
//
#include <hip/hip_runtime.h>
#include <math.h>

// 8-qubit statevector sim, 1 batch element per 64-lane wave.
// Lane holds 4 complex amps: flat index i = (k<<6) | lane, k in 0..3.
// Qubit q acts on bit p = 7-q of i. p in {6,7}: in-lane (k bits).
// p in {0..5}: cross-lane, partner lane = lane ^ (1<<p).

template<int P>
__device__ __forceinline__ void apply_gate(float (&ar)[4], float (&ai)[4], int lane,
    float m00r, float m00i, float m01r, float m01i,
    float m10r, float m10i, float m11r, float m11i)
{
    if constexpr (P >= 6) {
        constexpr int step = 1 << (P - 6);
        #pragma unroll
        for (int k0 = 0; k0 < 4; ++k0) {
            if (k0 & step) continue;
            const int k1 = k0 | step;
            float xr = ar[k0], xi = ai[k0];
            float yr = ar[k1], yi = ai[k1];
            ar[k0] = m00r*xr - m00i*xi + m01r*yr - m01i*yi;
            ai[k0] = m00r*xi + m00i*xr + m01r*yi + m01i*yr;
            ar[k1] = m10r*xr - m10i*xi + m11r*yr - m11i*yi;
            ai[k1] = m10r*xi + m10i*xr + m11r*yi + m11i*yr;
        }
    } else {
        constexpr int mask = 1 << P;
        const bool hi = (lane >> P) & 1;
        // lo lane: new = m00*x + m01*partner ; hi lane: new = m11*x + m10*partner
        const float car = hi ? m11r : m00r;
        const float cai = hi ? m11i : m00i;
        const float cbr = hi ? m10r : m01r;
        const float cbi = hi ? m10i : m01i;
        #pragma unroll
        for (int k = 0; k < 4; ++k) {
            float pr = __shfl_xor(ar[k], mask, 64);
            float pi = __shfl_xor(ai[k], mask, 64);
            float xr = ar[k], xi = ai[k];
            ar[k] = car*xr - cai*xi + cbr*pr - cbi*pi;
            ai[k] = car*xi + cai*xr + cbr*pi + cbi*pr;
        }
    }
}

// CNOT with control bit PC, target bit PT (bit positions in flat index).
template<int PC, int PT>
__device__ __forceinline__ void apply_cnot(float (&ar)[4], float (&ai)[4], int lane)
{
    if constexpr (PC >= 6 && PT >= 6) {
        constexpr int cb = 1 << (PC - 6);
        constexpr int tb = 1 << (PT - 6);
        #pragma unroll
        for (int k0 = 0; k0 < 4; ++k0) {
            if (!(k0 & cb)) continue;
            if (k0 & tb) continue;
            const int k1 = k0 | tb;
            float tr = ar[k0], ti = ai[k0];
            ar[k0] = ar[k1]; ai[k0] = ai[k1];
            ar[k1] = tr;     ai[k1] = ti;
        }
    } else if constexpr (PC >= 6) {
        // control in-lane (k bit), target cross-lane: swap across mask where k has cb
        constexpr int cb = 1 << (PC - 6);
        constexpr int mask = 1 << PT;
        #pragma unroll
        for (int k = 0; k < 4; ++k) {
            float tr = __shfl_xor(ar[k], mask, 64);
            float ti = __shfl_xor(ai[k], mask, 64);
            if (k & cb) { ar[k] = tr; ai[k] = ti; }  // k compile-time: dead shuffles elided
        }
    } else if constexpr (PT >= 6) {
        // control cross-lane, target in-lane: per-lane conditional register swap
        constexpr int tb = 1 << (PT - 6);
        const bool ctl = (lane >> PC) & 1;
        #pragma unroll
        for (int k0 = 0; k0 < 4; ++k0) {
            if (k0 & tb) continue;
            const int k1 = k0 | tb;
            float xr = ar[k0], xi = ai[k0], yr = ar[k1], yi = ai[k1];
            ar[k0] = ctl ? yr : xr;  ai[k0] = ctl ? yi : xi;
            ar[k1] = ctl ? xr : yr;  ai[k1] = ctl ? xi : yi;
        }
    } else {
        // both cross-lane: shuffle across target mask, take partner iff control bit set
        constexpr int mask = 1 << PT;
        const bool ctl = (lane >> PC) & 1;
        #pragma unroll
        for (int k = 0; k < 4; ++k) {
            float tr = __shfl_xor(ar[k], mask, 64);
            float ti = __shfl_xor(ai[k], mask, 64);
            if (ctl) { ar[k] = tr; ai[k] = ti; }
        }
    }
}

template<int Q>
__device__ __forceinline__ void rx_gate(float (&ar)[4], float (&ai)[4], int lane, float theta)
{
    float s, c;
    sincosf(theta * 0.5f, &s, &c);
    // RX: [[c, -i s], [-i s, c]]
    apply_gate<7 - Q>(ar, ai, lane,
                      c, 0.f,   0.f, -s,
                      0.f, -s,  c, 0.f);
}

template<int Q>
__device__ __forceinline__ void rot_gate(float (&ar)[4], float (&ai)[4], int lane,
                                         float phi, float theta, float omega)
{
    float st, ct; sincosf(theta * 0.5f, &st, &ct);
    float sa, ca; sincosf(0.5f * (phi + omega), &sa, &ca);   // ep = exp(-i a) = (ca, -sa)
    float sb, cb; sincosf(0.5f * (phi - omega), &sb, &cb);   // em = exp(+i b) = (cb, sb)
    // m00 = ep*ct, m01 = -em*st, m10 = conj(em)*st, m11 = conj(ep)*ct
    apply_gate<7 - Q>(ar, ai, lane,
                      ca*ct, -sa*ct,   -cb*st, -sb*st,
                      cb*st, -sb*st,    ca*ct,  sa*ct);
}

__global__ __launch_bounds__(256)
void qcirc_kernel(const float* __restrict__ inputs,
                  const float* __restrict__ hidden,
                  float* __restrict__ out, int B)
{
    const int lane = threadIdx.x & 63;
    const int wv   = threadIdx.x >> 6;
    const int b    = blockIdx.x * 4 + wv;
    if (b >= B) return;

    float ar[4], ai[4];
    #pragma unroll
    for (int k = 0; k < 4; ++k) { ar[k] = 0.f; ai[k] = 0.f; }
    if (lane == 0) ar[0] = 1.0f;   // |0...0>

    // ---- RX encoding layer ----
    const float* inb = inputs + (size_t)b * 8;
    rx_gate<0>(ar, ai, lane, inb[0]);
    rx_gate<1>(ar, ai, lane, inb[1]);
    rx_gate<2>(ar, ai, lane, inb[2]);
    rx_gate<3>(ar, ai, lane, inb[3]);
    rx_gate<4>(ar, ai, lane, inb[4]);
    rx_gate<5>(ar, ai, lane, inb[5]);
    rx_gate<6>(ar, ai, lane, inb[6]);
    rx_gate<7>(ar, ai, lane, inb[7]);

    // ---- 2 variational layers: Rot on each qubit + CNOT ring ----
    for (int l = 0; l < 2; ++l) {
        const float* w = hidden + (size_t)b * 48 + l * 24;  // (8 qubits, 3 angles)
        rot_gate<0>(ar, ai, lane, w[0],  w[1],  w[2]);
        rot_gate<1>(ar, ai, lane, w[3],  w[4],  w[5]);
        rot_gate<2>(ar, ai, lane, w[6],  w[7],  w[8]);
        rot_gate<3>(ar, ai, lane, w[9],  w[10], w[11]);
        rot_gate<4>(ar, ai, lane, w[12], w[13], w[14]);
        rot_gate<5>(ar, ai, lane, w[15], w[16], w[17]);
        rot_gate<6>(ar, ai, lane, w[18], w[19], w[20]);
        rot_gate<7>(ar, ai, lane, w[21], w[22], w[23]);

        // CNOT(c, t=c+1 mod 8): bit positions (7-c, 7-t)
        apply_cnot<7, 6>(ar, ai, lane);  // CNOT(0,1)
        apply_cnot<6, 5>(ar, ai, lane);  // CNOT(1,2)
        apply_cnot<5, 4>(ar, ai, lane);  // CNOT(2,3)
        apply_cnot<4, 3>(ar, ai, lane);  // CNOT(3,4)
        apply_cnot<3, 2>(ar, ai, lane);  // CNOT(4,5)
        apply_cnot<2, 1>(ar, ai, lane);  // CNOT(5,6)
        apply_cnot<1, 0>(ar, ai, lane);  // CNOT(6,7)
        apply_cnot<0, 7>(ar, ai, lane);  // CNOT(7,0)
    }

    // ---- expectation values of Z_q, then tanh ----
    float ev[8];
    #pragma unroll
    for (int q = 0; q < 8; ++q) ev[q] = 0.f;
    #pragma unroll
    for (int k = 0; k < 4; ++k) {
        const int i = (k << 6) | lane;
        const float p = ar[k]*ar[k] + ai[k]*ai[k];
        #pragma unroll
        for (int q = 0; q < 8; ++q) {
            ev[q] += ((i >> (7 - q)) & 1) ? -p : p;
        }
    }
    #pragma unroll
    for (int m = 1; m < 64; m <<= 1) {
        #pragma unroll
        for (int q = 0; q < 8; ++q) ev[q] += __shfl_xor(ev[q], m, 64);
    }
    if (lane == 0) {
        const size_t half = (size_t)B * 8;
        #pragma unroll
        for (int q = 0; q < 8; ++q) {
            float h = tanhf(ev[q]);
            out[(size_t)b * 8 + q]        = h;
            out[half + (size_t)b * 8 + q] = h;
        }
    }
}

extern "C" void kernel_launch(void* const* d_in, const int* in_sizes, int n_in,
                              void* d_out, int out_size, void* d_ws, size_t ws_size,
                              hipStream_t stream)
{
    const float* inputs = (const float*)d_in[0];   // (B, 8) fp32
    const float* hidden = (const float*)d_in[1];   // (B, 2, 1, 8, 3) fp32
    float* out = (float*)d_out;                    // (2, B, 8) fp32 (tuple (h,h))
    const int B = in_sizes[0] / 8;                 // 16384
    const int blocks = (B + 3) / 4;                // 4 waves/block, 1 element/wave
    hipLaunchKernelGGL(qcirc_kernel, dim3(blocks), dim3(256), 0, stream,
                       inputs, hidden, out, B);
}

// Round 2
// 49.355 us; speedup vs baseline: 1.5030x; 1.5030x over previous
//
#include <hip/hip_runtime.h>
#include <math.h>

// 8-qubit statevector sim, 1 batch element per 64-lane wave.
// Lane holds 4 complex amps: flat index i = (k<<6) | lane, k in 0..3.
// Qubit q acts on bit p = 7-q of i. p in {6,7}: in-lane (k bits).
// p in {0..5}: cross-lane, partner lane = lane ^ (1<<p).

__device__ __forceinline__ void fast_sincos(float x, float& s, float& c) {
    // v_sin/v_cos take revolutions; |x| here is a few radians -> well in range.
    const float r = x * 0.15915494309189535f;
    s = __builtin_amdgcn_sinf(r);
    c = __builtin_amdgcn_cosf(r);
}

__device__ __forceinline__ float fast_tanh(float x) {
    // |x| <= 1 here. tanh(x) = 1 - 2/(e^{2x}+1)
    const float t = __builtin_amdgcn_exp2f(x * 2.8853900817779268f); // e^{2x}
    return 1.0f - 2.0f * __builtin_amdgcn_rcpf(t + 1.0f);
}

template<int P>
__device__ __forceinline__ void apply_gate(float (&ar)[4], float (&ai)[4], int lane,
    float m00r, float m00i, float m01r, float m01i,
    float m10r, float m10i, float m11r, float m11i)
{
    if constexpr (P >= 6) {
        constexpr int step = 1 << (P - 6);
        #pragma unroll
        for (int k0 = 0; k0 < 4; ++k0) {
            if (k0 & step) continue;
            const int k1 = k0 | step;
            float xr = ar[k0], xi = ai[k0];
            float yr = ar[k1], yi = ai[k1];
            ar[k0] = m00r*xr - m00i*xi + m01r*yr - m01i*yi;
            ai[k0] = m00r*xi + m00i*xr + m01r*yi + m01i*yr;
            ar[k1] = m10r*xr - m10i*xi + m11r*yr - m11i*yi;
            ai[k1] = m10r*xi + m10i*xr + m11r*yi + m11i*yr;
        }
    } else {
        constexpr int mask = 1 << P;
        const bool hi = (lane >> P) & 1;
        const float car = hi ? m11r : m00r;
        const float cai = hi ? m11i : m00i;
        const float cbr = hi ? m10r : m01r;
        const float cbi = hi ? m10i : m01i;
        #pragma unroll
        for (int k = 0; k < 4; ++k) {
            float pr = __shfl_xor(ar[k], mask, 64);
            float pi = __shfl_xor(ai[k], mask, 64);
            float xr = ar[k], xi = ai[k];
            ar[k] = car*xr - cai*xi + cbr*pr - cbi*pi;
            ai[k] = car*xi + cai*xr + cbr*pi + cbi*pr;
        }
    }
}

// CNOT with control bit PC, target bit PT (bit positions in flat index).
template<int PC, int PT>
__device__ __forceinline__ void apply_cnot(float (&ar)[4], float (&ai)[4], int lane)
{
    if constexpr (PC >= 6 && PT >= 6) {
        constexpr int cb = 1 << (PC - 6);
        constexpr int tb = 1 << (PT - 6);
        #pragma unroll
        for (int k0 = 0; k0 < 4; ++k0) {
            if (!(k0 & cb)) continue;
            if (k0 & tb) continue;
            const int k1 = k0 | tb;
            float tr = ar[k0], ti = ai[k0];
            ar[k0] = ar[k1]; ai[k0] = ai[k1];
            ar[k1] = tr;     ai[k1] = ti;
        }
    } else if constexpr (PC >= 6) {
        constexpr int cb = 1 << (PC - 6);
        constexpr int mask = 1 << PT;
        #pragma unroll
        for (int k = 0; k < 4; ++k) {
            if (k & cb) {
                ar[k] = __shfl_xor(ar[k], mask, 64);
                ai[k] = __shfl_xor(ai[k], mask, 64);
            }
        }
    } else if constexpr (PT >= 6) {
        constexpr int tb = 1 << (PT - 6);
        const bool ctl = (lane >> PC) & 1;
        #pragma unroll
        for (int k0 = 0; k0 < 4; ++k0) {
            if (k0 & tb) continue;
            const int k1 = k0 | tb;
            float xr = ar[k0], xi = ai[k0], yr = ar[k1], yi = ai[k1];
            ar[k0] = ctl ? yr : xr;  ai[k0] = ctl ? yi : xi;
            ar[k1] = ctl ? xr : yr;  ai[k1] = ctl ? xi : yi;
        }
    } else {
        constexpr int mask = 1 << PT;
        const bool ctl = (lane >> PC) & 1;
        #pragma unroll
        for (int k = 0; k < 4; ++k) {
            float tr = __shfl_xor(ar[k], mask, 64);
            float ti = __shfl_xor(ai[k], mask, 64);
            if (ctl) { ar[k] = tr; ai[k] = ti; }
        }
    }
}

template<int Q>
__device__ __forceinline__ void rot_gate(float (&ar)[4], float (&ai)[4], int lane,
                                         float phi, float theta, float omega)
{
    float st, ct; fast_sincos(theta * 0.5f, st, ct);
    float sa, ca; fast_sincos(0.5f * (phi + omega), sa, ca);   // ep = exp(-i a) = (ca, -sa)
    float sb, cb; fast_sincos(0.5f * (phi - omega), sb, cb);   // em = exp(+i b) = (cb, sb)
    // m00 = ep*ct, m01 = -em*st, m10 = conj(em)*st, m11 = conj(ep)*ct
    apply_gate<7 - Q>(ar, ai, lane,
                      ca*ct, -sa*ct,   -cb*st, -sb*st,
                      cb*st, -sb*st,    ca*ct,  sa*ct);
}

__global__ __launch_bounds__(256)
void qcirc_kernel(const float* __restrict__ inputs,
                  const float* __restrict__ hidden,
                  float* __restrict__ out, int B)
{
    const int lane = threadIdx.x & 63;
    const int wv   = threadIdx.x >> 6;
    const int b    = __builtin_amdgcn_readfirstlane(blockIdx.x * 4 + wv);
    if (b >= B) return;

    // ---- RX encoding layer as direct product-state construction ----
    // RX(x)|0> = cos(x/2)|0> - i sin(x/2)|1>
    // amp(i) = [prod_p (bit_p(i) ? s_{7-p} : c_{7-p})] * (-i)^{popcount(i)}
    const float* inb = inputs + (size_t)b * 8;
    float sx[8], cx[8];
    #pragma unroll
    for (int q = 0; q < 8; ++q) fast_sincos(0.5f * inb[q], sx[q], cx[q]);

    float base = 1.0f;
    #pragma unroll
    for (int p = 0; p < 6; ++p) {
        base *= ((lane >> p) & 1) ? sx[7 - p] : cx[7 - p];
    }
    const int pop6 = __popc(lane);

    float ar[4], ai[4];
    #pragma unroll
    for (int k = 0; k < 4; ++k) {
        // bit6 of i = k&1 -> qubit 1 ; bit7 of i = k>>1 -> qubit 0
        const float m = base * ((k & 1) ? sx[1] : cx[1]) * ((k & 2) ? sx[0] : cx[0]);
        const int pop = (pop6 + (k & 1) + ((k >> 1) & 1)) & 3;
        ar[k] = (pop == 0) ? m : ((pop == 2) ? -m : 0.0f);
        ai[k] = (pop == 1) ? -m : ((pop == 3) ? m : 0.0f);
    }

    // ---- 2 variational layers: Rot on each qubit + CNOT ring ----
    #pragma unroll
    for (int l = 0; l < 2; ++l) {
        const float* w = hidden + (size_t)b * 48 + l * 24;  // (8 qubits, 3 angles)
        rot_gate<0>(ar, ai, lane, w[0],  w[1],  w[2]);
        rot_gate<1>(ar, ai, lane, w[3],  w[4],  w[5]);
        rot_gate<2>(ar, ai, lane, w[6],  w[7],  w[8]);
        rot_gate<3>(ar, ai, lane, w[9],  w[10], w[11]);
        rot_gate<4>(ar, ai, lane, w[12], w[13], w[14]);
        rot_gate<5>(ar, ai, lane, w[15], w[16], w[17]);
        rot_gate<6>(ar, ai, lane, w[18], w[19], w[20]);
        rot_gate<7>(ar, ai, lane, w[21], w[22], w[23]);

        apply_cnot<7, 6>(ar, ai, lane);  // CNOT(0,1)
        apply_cnot<6, 5>(ar, ai, lane);  // CNOT(1,2)
        apply_cnot<5, 4>(ar, ai, lane);  // CNOT(2,3)
        apply_cnot<4, 3>(ar, ai, lane);  // CNOT(3,4)
        apply_cnot<3, 2>(ar, ai, lane);  // CNOT(4,5)
        apply_cnot<2, 1>(ar, ai, lane);  // CNOT(5,6)
        apply_cnot<1, 0>(ar, ai, lane);  // CNOT(6,7)
        apply_cnot<0, 7>(ar, ai, lane);  // CNOT(7,0)
    }

    // ---- expectation values of Z_q, then tanh ----
    float p0 = ar[0]*ar[0] + ai[0]*ai[0];
    float p1 = ar[1]*ar[1] + ai[1]*ai[1];
    float p2 = ar[2]*ar[2] + ai[2]*ai[2];
    float p3 = ar[3]*ar[3] + ai[3]*ai[3];

    float T  = (p0 + p1) + (p2 + p3);   // sign indep of k-bits
    float U0 = (p0 + p1) - (p2 + p3);   // qubit 0 sign = bit7 = k>>1
    float U1 = (p0 - p1) + (p2 - p3);   // qubit 1 sign = bit6 = k&1

    // Full sums over lanes for U0, U1 (qubits 0,1)
    #pragma unroll
    for (int m = 1; m < 64; m <<= 1) {
        U0 += __shfl_xor(U0, m, 64);
        U1 += __shfl_xor(U1, m, 64);
    }

    // FWHT over lanes on T: afterwards lane (1<<p) holds
    // sum_lane (-1)^{bit_p(lane)} T(lane) = ev of qubit 7-p  (p=0..5)
    float wv_ = T;
    #pragma unroll
    for (int m = 1; m < 64; m <<= 1) {
        float o = __shfl_xor(wv_, m, 64);
        wv_ = (lane & m) ? (o - wv_) : (o + wv_);
    }

    const size_t obase = (size_t)b * 8;
    const size_t half  = (size_t)B * 8;
    if (lane == 0) {
        const float h0 = fast_tanh(U0);
        const float h1 = fast_tanh(U1);
        out[obase + 0] = h0; out[half + obase + 0] = h0;
        out[obase + 1] = h1; out[half + obase + 1] = h1;
    }
    if (__popc(lane) == 1 && lane <= 32) {
        const int p = 31 - __clz(lane);      // lane = 1<<p
        const float h = fast_tanh(wv_);
        out[obase + 7 - p] = h; out[half + obase + 7 - p] = h;
    }
}

extern "C" void kernel_launch(void* const* d_in, const int* in_sizes, int n_in,
                              void* d_out, int out_size, void* d_ws, size_t ws_size,
                              hipStream_t stream)
{
    const float* inputs = (const float*)d_in[0];   // (B, 8) fp32
    const float* hidden = (const float*)d_in[1];   // (B, 2, 1, 8, 3) fp32
    float* out = (float*)d_out;                    // (2, B, 8) fp32 (tuple (h,h))
    const int B = in_sizes[0] / 8;                 // 16384
    const int blocks = (B + 3) / 4;                // 4 waves/block, 1 element/wave
    hipLaunchKernelGGL(qcirc_kernel, dim3(blocks), dim3(256), 0, stream,
                       inputs, hidden, out, B);
}

// Round 3
// 44.009 us; speedup vs baseline: 1.6856x; 1.1215x over previous
//
#include <hip/hip_runtime.h>
#include <math.h>

// 8-qubit statevector sim, 1 batch element per 64-lane wave.
// Lane holds 4 complex amps: physical index y = (k<<6) | lane, k in 0..3.
// CNOT rings are ELIMINATED: they are linear (GF(2)) basis relabelings with a
// compile-time map. We track  amp_logical[x] = P[A x]  and apply each Rot with
// pairing mask m = A*e_p and hi-selector row r = row_p(A^{-1}).
//   Layer 1: A = I        -> m = e_p,     r = e_p
//   Layer 2: A = C        -> m = C e_p,   r = row_p(C^{-1})
//   Epilogue: A = C^2     -> Z_q sign mask s = row_{7-q}(C^{-2})
// where C is the CNOT-ring composite: j0=x0^x1, j1=x1^x2, ..., j5=x5^x6,
// j6=x6^x7^x0, j7=x7^x0.

__device__ __forceinline__ void fast_sincos_half(float x, float& s, float& c) {
    // sin/cos of x/2 via HW ops (input in revolutions)
    const float r = x * 0.07957747154594767f;   // 0.5 / (2*pi)
    s = __builtin_amdgcn_sinf(r);
    c = __builtin_amdgcn_cosf(r);
}

__device__ __forceinline__ float fast_tanh(float x) {
    // |x| <= 1 here. tanh(x) = 1 - 2/(e^{2x}+1)
    const float t = __builtin_amdgcn_exp2f(x * 2.8853900817779268f); // e^{2x}
    return 1.0f - 2.0f * __builtin_amdgcn_rcpf(t + 1.0f);
}

// Unified gate apply. Pair of y=(k,lane) is (k^KM, lane^LM).
// hi(y) = hl ^ (popc(k & KSEL) & 1). hl is the lane-part parity (runtime,
// uniform over k); KSEL selects are compile-time per k.
template<int LM, int KM, int KSEL>
__device__ __forceinline__ void gate_any(float (&ar)[4], float (&ai)[4], bool hl,
    float m00r, float m00i, float m01r, float m01i,
    float m10r, float m10i, float m11r, float m11i)
{
    // coefficient set A: for k with kpar==0 (hi = hl)
    const float carA = hl ? m11r : m00r;
    const float caiA = hl ? m11i : m00i;
    const float cbrA = hl ? m10r : m01r;
    const float cbiA = hl ? m10i : m01i;
    // coefficient set B: for k with kpar==1 (hi = !hl)
    const float carB = hl ? m00r : m11r;
    const float caiB = hl ? m00i : m11i;
    const float cbrB = hl ? m01r : m10r;
    const float cbiB = hl ? m01i : m10i;

    float xr[4], xi[4];
    #pragma unroll
    for (int k = 0; k < 4; ++k) { xr[k] = ar[k]; xi[k] = ai[k]; }

    #pragma unroll
    for (int k = 0; k < 4; ++k) {
        float pr, pi;
        if constexpr (LM != 0) {
            pr = __shfl_xor(xr[k ^ KM], LM, 64);
            pi = __shfl_xor(xi[k ^ KM], LM, 64);
        } else {
            pr = xr[k ^ KM];
            pi = xi[k ^ KM];
        }
        constexpr bool KP0 = false;
        const bool kp = (__builtin_popcount(k & KSEL) & 1) != 0;
        (void)KP0;
        const float car = kp ? carB : carA;
        const float cai = kp ? caiB : caiA;
        const float cbr = kp ? cbrB : cbrA;
        const float cbi = kp ? cbiB : cbiA;
        ar[k] = car*xr[k] - cai*xi[k] + cbr*pr - cbi*pi;
        ai[k] = car*xi[k] + cai*xr[k] + cbr*pi + cbi*pr;
    }
}

template<int LM, int KM, int KSEL>
__device__ __forceinline__ void rot_gate(float (&ar)[4], float (&ai)[4], bool hl,
                                         float phi, float theta, float omega)
{
    float st, ct; fast_sincos_half(theta, st, ct);
    float sa, ca; fast_sincos_half(phi + omega, sa, ca);   // ep = exp(-ia) = (ca,-sa)
    float sb, cb; fast_sincos_half(phi - omega, sb, cb);   // em = exp(+ib) = (cb, sb)
    // m00 = ep*ct, m01 = -em*st, m10 = conj(em)*st, m11 = conj(ep)*ct
    gate_any<LM, KM, KSEL>(ar, ai, hl,
                           ca*ct, -sa*ct,   -cb*st, -sb*st,
                           cb*st, -sb*st,    ca*ct,  sa*ct);
}

__global__ __launch_bounds__(256)
void qcirc_kernel(const float* __restrict__ inputs,
                  const float* __restrict__ hidden,
                  float* __restrict__ out, int B)
{
    const int lane = threadIdx.x & 63;
    const int wv   = threadIdx.x >> 6;
    const int b    = __builtin_amdgcn_readfirstlane(blockIdx.x * 4 + wv);
    if (b >= B) return;

    // ---- RX encoding layer: direct product-state construction ----
    const float* inb = inputs + (size_t)b * 8;
    float sx[8], cx[8];
    #pragma unroll
    for (int q = 0; q < 8; ++q) fast_sincos_half(inb[q], sx[q], cx[q]);

    float base = 1.0f;
    #pragma unroll
    for (int p = 0; p < 6; ++p) {
        base *= ((lane >> p) & 1) ? sx[7 - p] : cx[7 - p];
    }
    const int pop6 = __popc(lane);

    float ar[4], ai[4];
    #pragma unroll
    for (int k = 0; k < 4; ++k) {
        // bit6 = k&1 -> qubit 1 ; bit7 = k>>1 -> qubit 0
        const float m = base * ((k & 1) ? sx[1] : cx[1]) * ((k & 2) ? sx[0] : cx[0]);
        const int pop = (pop6 + (k & 1) + ((k >> 1) & 1)) & 3;
        ar[k] = (pop == 0) ? m : ((pop == 2) ? -m : 0.0f);
        ai[k] = (pop == 1) ? -m : ((pop == 3) ? m : 0.0f);
    }

    const int par6 = __popc(lane & 0x3F) & 1;   // parity of all lane bits

    // ---- Layer 1 Rots (A = I): mask e_p, selector e_p ----
    {
        const float* w = hidden + (size_t)b * 48;
        rot_gate<0x00, 2, 2>(ar, ai, false,          w[0],  w[1],  w[2]);   // q0 (bit7)
        rot_gate<0x00, 1, 1>(ar, ai, false,          w[3],  w[4],  w[5]);   // q1 (bit6)
        rot_gate<0x20, 0, 0>(ar, ai, (lane>>5) & 1,  w[6],  w[7],  w[8]);   // q2
        rot_gate<0x10, 0, 0>(ar, ai, (lane>>4) & 1,  w[9],  w[10], w[11]);  // q3
        rot_gate<0x08, 0, 0>(ar, ai, (lane>>3) & 1,  w[12], w[13], w[14]);  // q4
        rot_gate<0x04, 0, 0>(ar, ai, (lane>>2) & 1,  w[15], w[16], w[17]);  // q5
        rot_gate<0x02, 0, 0>(ar, ai, (lane>>1) & 1,  w[18], w[19], w[20]);  // q6
        rot_gate<0x01, 0, 0>(ar, ai, lane & 1,       w[21], w[22], w[23]);  // q7
    }
    // Layer-1 CNOT ring: eliminated (basis relabeling, A <- C)

    // ---- Layer 2 Rots (A = C): mask = C e_p, selector = row_p(C^{-1}) ----
    {
        const float* w = hidden + (size_t)b * 48 + 24;
        rot_gate<0x00, 3, 1>(ar, ai, par6,                     w[0],  w[1],  w[2]);   // q0: m=0xC0, r=0x7F
        rot_gate<0x20, 1, 3>(ar, ai, false,                    w[3],  w[4],  w[5]);   // q1: m=0x60, r=0xC0
        rot_gate<0x30, 0, 3>(ar, ai, (lane>>5) & 1,            w[6],  w[7],  w[8]);   // q2: m=0x30, r=0xE0
        rot_gate<0x18, 0, 3>(ar, ai, __popc(lane & 0x30) & 1,  w[9],  w[10], w[11]);  // q3: m=0x18, r=0xF0
        rot_gate<0x0C, 0, 3>(ar, ai, __popc(lane & 0x38) & 1,  w[12], w[13], w[14]);  // q4: m=0x0C, r=0xF8
        rot_gate<0x06, 0, 3>(ar, ai, __popc(lane & 0x3C) & 1,  w[15], w[16], w[17]);  // q5: m=0x06, r=0xFC
        rot_gate<0x03, 0, 3>(ar, ai, __popc(lane & 0x3E) & 1,  w[18], w[19], w[20]);  // q6: m=0x03, r=0xFE
        rot_gate<0x01, 3, 3>(ar, ai, par6,                     w[21], w[22], w[23]);  // q7: m=0xC1, r=0xFF
    }
    // Layer-2 CNOT ring: eliminated (A <- C^2, absorbed into epilogue masks)

    // ---- Z expectations via Walsh coefficients at s = rows of C^{-2} ----
    // s (by qubit): q0:0xD5 q1:0xBF q2:0x5F q3:0xAF q4:0x57 q5:0xAB q6:0x55 q7:0xAA
    const float p0 = ar[0]*ar[0] + ai[0]*ai[0];
    const float p1 = ar[1]*ar[1] + ai[1]*ai[1];
    const float p2 = ar[2]*ar[2] + ai[2]*ai[2];
    const float p3 = ar[3]*ar[3] + ai[3]*ai[3];

    float V1 = (p0 - p1) + (p2 - p3);   // k-sign (-1)^{k&1}      (k-part 01)
    float V2 = (p0 + p1) - (p2 + p3);   // k-sign (-1)^{k>>1}     (k-part 10)
    float V3 = (p0 - p1) - (p2 - p3);   // k-sign (-1)^{popc(k)}  (k-part 11)

    // FWHT over lanes: afterwards lane t holds sum_l (-1)^{popc(l&t)} V(l)
    #pragma unroll
    for (int m = 1; m < 64; m <<= 1) {
        const float o1 = __shfl_xor(V1, m, 64);
        const float o2 = __shfl_xor(V2, m, 64);
        const float o3 = __shfl_xor(V3, m, 64);
        if (lane & m) { V1 = o1 - V1; V2 = o2 - V2; V3 = o3 - V3; }
        else          { V1 = o1 + V1; V2 = o2 + V2; V3 = o3 + V3; }
    }

    const size_t obase = (size_t)b * 8;
    const size_t half  = (size_t)B * 8;

    int q = -1; float v = 0.f;
    if (lane == 21) { q = 6; v = V1; }   // s=0x55: lane 0x15, k 01
    if (lane == 23) { q = 4; v = V1; }   // s=0x57: lane 0x17, k 01
    if (lane == 31) { q = 2; v = V1; }   // s=0x5F: lane 0x1F, k 01
    if (lane == 42) { q = 7; v = V2; }   // s=0xAA: lane 0x2A, k 10
    if (lane == 43) { q = 5; v = V2; }   // s=0xAB: lane 0x2B, k 10
    if (lane == 47) { q = 3; v = V2; }   // s=0xAF: lane 0x2F, k 10
    if (lane == 63) { q = 1; v = V2; }   // s=0xBF: lane 0x3F, k 10
    if (q >= 0) {
        const float h = fast_tanh(v);
        out[obase + q] = h;
        out[half + obase + q] = h;
    }
    if (lane == 21) {                    // s=0xD5: lane 0x15, k 11 -> q0
        const float h = fast_tanh(V3);
        out[obase + 0] = h;
        out[half + obase + 0] = h;
    }
}

extern "C" void kernel_launch(void* const* d_in, const int* in_sizes, int n_in,
                              void* d_out, int out_size, void* d_ws, size_t ws_size,
                              hipStream_t stream)
{
    const float* inputs = (const float*)d_in[0];   // (B, 8) fp32
    const float* hidden = (const float*)d_in[1];   // (B, 2, 1, 8, 3) fp32
    float* out = (float*)d_out;                    // (2, B, 8) fp32 (tuple (h,h))
    const int B = in_sizes[0] / 8;                 // 16384
    const int blocks = (B + 3) / 4;                // 4 waves/block, 1 element/wave
    hipLaunchKernelGGL(qcirc_kernel, dim3(blocks), dim3(256), 0, stream,
                       inputs, hidden, out, B);
}

// Round 4
// 24.958 us; speedup vs baseline: 2.9722x; 1.7633x over previous
//
#include <hip/hip_runtime.h>
#include <math.h>

// 8-qubit statevector sim, FOUR batch elements per 64-lane wave.
// Each 16-lane group owns one element; lane holds 16 complex amps:
// physical index y = (k<<4) | sl, sl = lane&15 (4 bits), k = reg idx (4 bits).
// Bit p of y: p=0..3 -> sl bits (qubits 7..4), p=4..7 -> k bits (qubits 3..0).
//
// Structure exploited:
//  (a) RX layer + layer-1 Rots are all 1-qubit gates -> state before first
//      CNOT ring is a PRODUCT state; built directly from per-qubit 2-vectors.
//  (b) CNOT rings are GF(2) basis relabelings (test-validated rounds 2-3):
//      layer-2 Rot on qubit p pairs physical mask m = C e_p with hi-selector
//      r = row_p(C^{-1}); Z_q sign masks s = rows of C^{-2}.
//      m/r (bit7..0): q0:C0/7F q1:60/C0 q2:30/E0 q3:18/F0 q4:0C/F8 q5:06/FC
//                     q6:03/FE q7:C1/FF ; s: D5,BF,5F,AF,57,AB,55,AA.

#define DEVINL __device__ __forceinline__

DEVINL void fast_sincos_half(float x, float& s, float& c) {
    const float r = x * 0.07957747154594767f;   // (x/2) / (2*pi), HW sin/cos in revolutions
    s = __builtin_amdgcn_sinf(r);
    c = __builtin_amdgcn_cosf(r);
}

DEVINL float fast_tanh(float x) {
    // |x| <= 1 here. tanh(x) = 1 - 2/(e^{2x}+1)
    const float t = __builtin_amdgcn_exp2f(x * 2.8853900817779268f);
    return 1.0f - 2.0f * __builtin_amdgcn_rcpf(t + 1.0f);
}

// v = Rot(phi,theta,omega) * RX(x) * |0>
DEVINL void qubit_vec(float x, float phi, float theta, float omega,
                      float& v0r, float& v0i, float& v1r, float& v1i)
{
    float s, c;   fast_sincos_half(x, s, c);
    float st, ct; fast_sincos_half(theta, st, ct);
    float sa, ca; fast_sincos_half(phi + omega, sa, ca);   // ep = (ca,-sa)
    float sb, cb; fast_sincos_half(phi - omega, sb, cb);   // em = (cb, sb)
    const float A = c*ct, B = s*st, C = c*st, D = s*ct;
    v0r = ca*A - sb*B;
    v0i = cb*B - sa*A;
    v1r = cb*C + sa*D;
    v1i = -(sb*C + ca*D);
}

// Rot gate on state[16]: pairing (k^KM, sl^LM); hi = hl ^ parity(k & KSEL).
// Update: nr = act*xr + S*sact*xi - S*cbst*pr + sbst*pi
//         ni = act*xi - S*sact*xr - S*cbst*pi - sbst*pr,  S=+1(hi=0)/-1(hi=1)
template<int LM, int KM, int KSEL>
DEVINL void rot16(float (&ar)[16], float (&ai)[16], bool hl,
                  float phi, float theta, float omega)
{
    float st, ct; fast_sincos_half(theta, st, ct);
    float sa, ca; fast_sincos_half(phi + omega, sa, ca);
    float sb, cb; fast_sincos_half(phi - omega, sb, cb);
    const float act  = ca*ct;
    const float sbst = sb*st;
    const float sact = sa*ct;
    const float cbst = cb*st;
    const float u0 = hl ? -sact : sact;   // S*sact for kp=0
    const float v0 = hl ? -cbst : cbst;   // S*cbst for kp=0

    if constexpr (KM == 0) {
        #pragma unroll
        for (int k = 0; k < 16; ++k) {
            const bool kp = (__builtin_popcount(k & KSEL) & 1) != 0;  // compile-time
            const float u = kp ? -u0 : u0;
            const float v = kp ? -v0 : v0;
            const float pr = __shfl_xor(ar[k], LM, 64);
            const float pi = __shfl_xor(ai[k], LM, 64);
            const float xr = ar[k], xi = ai[k];
            ar[k] = act*xr + u*xi - v*pr + sbst*pi;
            ai[k] = act*xi - u*xr - v*pi - sbst*pr;
        }
    } else {
        constexpr int HB = (KM & 8) ? 8 : ((KM & 4) ? 4 : ((KM & 2) ? 2 : 1));
        #pragma unroll
        for (int k0 = 0; k0 < 16; ++k0) {
            if (k0 & HB) continue;
            const int k1 = k0 ^ KM;
            const bool kp0 = (__builtin_popcount(k0 & KSEL) & 1) != 0;
            const bool kp1 = (__builtin_popcount(k1 & KSEL) & 1) != 0;
            float p0r, p0i, p1r, p1i;
            if constexpr (LM != 0) {
                p0r = __shfl_xor(ar[k1], LM, 64);
                p0i = __shfl_xor(ai[k1], LM, 64);
                p1r = __shfl_xor(ar[k0], LM, 64);
                p1i = __shfl_xor(ai[k0], LM, 64);
            } else {
                p0r = ar[k1]; p0i = ai[k1];
                p1r = ar[k0]; p1i = ai[k0];
            }
            const float x0r = ar[k0], x0i = ai[k0];
            const float x1r = ar[k1], x1i = ai[k1];
            const float u0k = kp0 ? -u0 : u0, v0k = kp0 ? -v0 : v0;
            const float u1k = kp1 ? -u0 : u0, v1k = kp1 ? -v0 : v0;
            ar[k0] = act*x0r + u0k*x0i - v0k*p0r + sbst*p0i;
            ai[k0] = act*x0i - u0k*x0r - v0k*p0i - sbst*p0r;
            ar[k1] = act*x1r + u1k*x1i - v1k*p1r + sbst*p1i;
            ai[k1] = act*x1i - u1k*x1r - v1k*p1i - sbst*p1r;
        }
    }
}

__global__ __launch_bounds__(256, 4)
void qcirc_kernel(const float* __restrict__ inputs,
                  const float* __restrict__ hidden,
                  float* __restrict__ out, int B)
{
    const int tid = blockIdx.x * 256 + threadIdx.x;
    const int e   = tid >> 4;               // one element per 16 lanes
    const int sl  = threadIdx.x & 15;
    if (e >= B) return;

    // ---- vectorized loads of this element's 56 scalars ----
    float inv[8], w1v[24], w2v[24];
    {
        const float4* ip = (const float4*)(inputs + (size_t)e * 8);
        ((float4*)inv)[0] = ip[0];
        ((float4*)inv)[1] = ip[1];
        const float4* hp = (const float4*)(hidden + (size_t)e * 48);
        #pragma unroll
        for (int j = 0; j < 6; ++j) ((float4*)w1v)[j] = hp[j];
        #pragma unroll
        for (int j = 0; j < 6; ++j) ((float4*)w2v)[j] = hp[6 + j];
    }

    // ---- lane-part product: qubits 7,6,5,4 selected by sl bits 0,1,2,3 ----
    float br, bi;
    {
        float a0r,a0i,a1r,a1i;
        qubit_vec(inv[7], w1v[21], w1v[22], w1v[23], a0r,a0i,a1r,a1i);
        br = (sl & 1) ? a1r : a0r;
        bi = (sl & 1) ? a1i : a0i;
        qubit_vec(inv[6], w1v[18], w1v[19], w1v[20], a0r,a0i,a1r,a1i);
        float xr = (sl & 2) ? a1r : a0r, xi = (sl & 2) ? a1i : a0i;
        float nr = br*xr - bi*xi, ni = br*xi + bi*xr; br = nr; bi = ni;
        qubit_vec(inv[5], w1v[15], w1v[16], w1v[17], a0r,a0i,a1r,a1i);
        xr = (sl & 4) ? a1r : a0r; xi = (sl & 4) ? a1i : a0i;
        nr = br*xr - bi*xi; ni = br*xi + bi*xr; br = nr; bi = ni;
        qubit_vec(inv[4], w1v[12], w1v[13], w1v[14], a0r,a0i,a1r,a1i);
        xr = (sl & 8) ? a1r : a0r; xi = (sl & 8) ? a1i : a0i;
        nr = br*xr - bi*xi; ni = br*xi + bi*xr; br = nr; bi = ni;
    }

    // ---- k-part products: k bit0->q3, bit1->q2, bit2->q1, bit3->q0 ----
    float tLr[4], tLi[4], tHr[4], tHii[4];
    {
        float b0r,b0i,b1r,b1i, c0r,c0i,c1r,c1i;
        qubit_vec(inv[3], w1v[9],  w1v[10], w1v[11], b0r,b0i,b1r,b1i);  // q3
        qubit_vec(inv[2], w1v[6],  w1v[7],  w1v[8],  c0r,c0i,c1r,c1i);  // q2
        #pragma unroll
        for (int j = 0; j < 4; ++j) {
            const float xr = (j & 1) ? b1r : b0r, xi = (j & 1) ? b1i : b0i;
            const float yr = (j & 2) ? c1r : c0r, yi = (j & 2) ? c1i : c0i;
            const float pr = xr*yr - xi*yi, pi = xr*yi + xi*yr;
            tLr[j] = pr*br - pi*bi;          // fold lane base in
            tLi[j] = pr*bi + pi*br;
        }
        qubit_vec(inv[1], w1v[3],  w1v[4],  w1v[5],  b0r,b0i,b1r,b1i);  // q1
        qubit_vec(inv[0], w1v[0],  w1v[1],  w1v[2],  c0r,c0i,c1r,c1i);  // q0
        #pragma unroll
        for (int j = 0; j < 4; ++j) {
            const float xr = (j & 1) ? b1r : b0r, xi = (j & 1) ? b1i : b0i;
            const float yr = (j & 2) ? c1r : c0r, yi = (j & 2) ? c1i : c0i;
            tHr[j]  = xr*yr - xi*yi;
            tHii[j] = xr*yi + xi*yr;
        }
    }

    // ---- initial state = full product (post RX + layer-1 Rots) ----
    float ar[16], ai[16];
    #pragma unroll
    for (int k = 0; k < 16; ++k) {
        const float lr = tLr[k & 3],  li = tLi[k & 3];
        const float hr = tHr[k >> 2], hi2 = tHii[k >> 2];
        ar[k] = lr*hr - li*hi2;
        ai[k] = lr*hi2 + li*hr;
    }

    // ---- layer-2 Rots in C-relabeled basis ----
    const bool pF = (__popc(sl & 0xF) & 1) != 0;
    const bool pC = (__popc(sl & 0xC) & 1) != 0;
    const bool pE = (__popc(sl & 0xE) & 1) != 0;
    const bool p8 = ((sl >> 3) & 1) != 0;

    rot16<0x0, 0xC, 0x7>(ar, ai, pF,    w2v[0],  w2v[1],  w2v[2]);   // q0: m=C0 r=7F
    rot16<0x0, 0x6, 0xC>(ar, ai, false, w2v[3],  w2v[4],  w2v[5]);   // q1: m=60 r=C0
    rot16<0x0, 0x3, 0xE>(ar, ai, false, w2v[6],  w2v[7],  w2v[8]);   // q2: m=30 r=E0
    rot16<0x8, 0x1, 0xF>(ar, ai, false, w2v[9],  w2v[10], w2v[11]);  // q3: m=18 r=F0
    rot16<0xC, 0x0, 0xF>(ar, ai, p8,    w2v[12], w2v[13], w2v[14]);  // q4: m=0C r=F8
    rot16<0x6, 0x0, 0xF>(ar, ai, pC,    w2v[15], w2v[16], w2v[17]);  // q5: m=06 r=FC
    rot16<0x3, 0x0, 0xF>(ar, ai, pE,    w2v[18], w2v[19], w2v[20]);  // q6: m=03 r=FE
    rot16<0x1, 0xC, 0xF>(ar, ai, pF,    w2v[21], w2v[22], w2v[23]);  // q7: m=C1 r=FF

    // ---- Z expectations: Walsh coefficients at s = rows of C^{-2} ----
    // s_hi (k-part) in {0xD,0xB,0x5,0xA}; s_lo (sl-part) per qubit below.
    float P[16];
    #pragma unroll
    for (int k = 0; k < 16; ++k) P[k] = ar[k]*ar[k] + ai[k]*ai[k];

    // k-part partial Walsh sums, grouped by j=(b3<<1)|b1, inner (b2,b0)
    float g0[4], g1[4], g5[4];
    #pragma unroll
    for (int j = 0; j < 4; ++j) {
        const int b3 = (j >> 1) & 1, b1 = j & 1;
        const float p00 = P[b3*8 + b1*2 + 0];
        const float p01 = P[b3*8 + b1*2 + 1];
        const float p10 = P[b3*8 + 4 + b1*2 + 0];
        const float p11 = P[b3*8 + 4 + b1*2 + 1];
        const float u = p00 + p01, v = p00 - p01;
        const float x = p10 + p11, y = p10 - p11;
        g0[j] = u + x;   // no inner sign
        g1[j] = v + y;   // (-1)^{b0}
        g5[j] = v - y;   // (-1)^{b0+b2}
    }
    const float s0 = g5[0] + g5[1], s1 = g5[2] + g5[3];
    float V5 = s0 + s1;                               // mask 0x5
    float VD = s0 - s1;                               // mask 0xD
    float VA = (g0[0] - g0[1]) - (g0[2] - g0[3]);     // mask 0xA
    float VB = (g1[0] - g1[1]) - (g1[2] - g1[3]);     // mask 0xB

    // FWHT over the 4 sl bits (stays within each 16-lane group)
    #pragma unroll
    for (int m = 1; m < 16; m <<= 1) {
        const float o5 = __shfl_xor(V5, m, 64);
        const float oA = __shfl_xor(VA, m, 64);
        const float oB = __shfl_xor(VB, m, 64);
        const float oD = __shfl_xor(VD, m, 64);
        if (sl & m) { V5 = o5 - V5; VA = oA - VA; VB = oB - VB; VD = oD - VD; }
        else        { V5 = o5 + V5; VA = oA + VA; VB = oB + VB; VD = oD + VD; }
    }

    // lane sl==s_lo holds the coefficient; write tanh to both output copies
    const size_t obase = (size_t)e * 8;
    const size_t half  = (size_t)B * 8;
    if (sl == 0x5) {
        const float h0 = fast_tanh(VD);   // q0 (s=0xD5)
        const float h6 = fast_tanh(V5);   // q6 (s=0x55)
        out[obase + 0] = h0; out[half + obase + 0] = h0;
        out[obase + 6] = h6; out[half + obase + 6] = h6;
    } else if (sl == 0x7) {
        const float h = fast_tanh(V5);    // q4 (s=0x57)
        out[obase + 4] = h; out[half + obase + 4] = h;
    } else if (sl == 0xA) {
        const float h = fast_tanh(VA);    // q7 (s=0xAA)
        out[obase + 7] = h; out[half + obase + 7] = h;
    } else if (sl == 0xB) {
        const float h = fast_tanh(VA);    // q5 (s=0xAB)
        out[obase + 5] = h; out[half + obase + 5] = h;
    } else if (sl == 0xF) {
        const float h1 = fast_tanh(VB);   // q1 (s=0xBF)
        const float h2 = fast_tanh(V5);   // q2 (s=0x5F)
        const float h3 = fast_tanh(VA);   // q3 (s=0xAF)
        out[obase + 1] = h1; out[half + obase + 1] = h1;
        out[obase + 2] = h2; out[half + obase + 2] = h2;
        out[obase + 3] = h3; out[half + obase + 3] = h3;
    }
}

extern "C" void kernel_launch(void* const* d_in, const int* in_sizes, int n_in,
                              void* d_out, int out_size, void* d_ws, size_t ws_size,
                              hipStream_t stream)
{
    const float* inputs = (const float*)d_in[0];   // (B, 8) fp32
    const float* hidden = (const float*)d_in[1];   // (B, 2, 1, 8, 3) fp32
    float* out = (float*)d_out;                    // (2, B, 8) fp32 (tuple (h,h))
    const int B = in_sizes[0] / 8;                 // 16384
    const int blocks = (B * 16 + 255) / 256;       // 16 threads per element
    hipLaunchKernelGGL(qcirc_kernel, dim3(blocks), dim3(256), 0, stream,
                       inputs, hidden, out, B);
}

// Round 5
// 15.672 us; speedup vs baseline: 4.7332x; 1.5925x over previous
//
#include <hip/hip_runtime.h>
#include <math.h>

// 8-qubit statevector sim, FOUR elements per 64-lane wave (16 lanes each).
// Storage index z (8 bits): z0-3 = lane-in-group sl, z4-7 = register k.
// A compile-time GF(2) map T (on top of the validated CNOT-ring relabeling C)
// was chosen so that:
//   layer-2 RY pair masks:   q0-q3 -> k-bits 8,4,2,1 (register swap, no lanes)
//                            q4-q7 -> lane xor 15,7,3,1  (ALL DPP patterns)
//   gate hi-selectors == pairing bit (q0-q3) / sl3, sl3^sl2, sl2^sl1, sl1^sl0
//   Z-measure Walsh masks: k-parts {7,C,E,F}, lane picks {1,0,0,0,8,4,2,1}
// Product-state selectors (original qubit -> z bits):
//   q0: sl0^sl1^k3   q1: sl0^sl1^k2^k3   q2: k1^k2   q3: k0^k1
//   q4: sl3^k0       q5: sl2             q6: sl1^sl3 q7: sl0^sl2
// Layer-2 Rot = RZ(w)RY(th)RZ(phi): RZ(w) provably cancels in |amp|^2;
// all RZ(phi) commute to the front -> one phase diagonal folded into init.

#define DEVINL __device__ __forceinline__

DEVINL void fast_sincos_half(float x, float& s, float& c) {
    const float r = x * 0.07957747154594767f;   // (x/2)/(2*pi): HW trig in revolutions
    s = __builtin_amdgcn_sinf(r);
    c = __builtin_amdgcn_cosf(r);
}

DEVINL float fast_tanh(float x) {
    const float t = __builtin_amdgcn_exp2f(x * 2.8853900817779268f);  // e^{2x}
    return 1.0f - 2.0f * __builtin_amdgcn_rcpf(t + 1.0f);
}

DEVINL void cmul(float ar, float ai, float br, float bi, float& cr, float& ci) {
    cr = ar*br - ai*bi;
    ci = ar*bi + ai*br;
}

template<int CTRL>
DEVINL float dpp_perm(float x) {
    return __int_as_float(__builtin_amdgcn_update_dpp(
        __float_as_int(x), __float_as_int(x), CTRL, 0xF, 0xF, false));
}
// DPP ctrls: xor1=quad_perm(1,0,3,2)=0xB1; xor2=quad_perm(2,3,0,1)=0x4E;
//            xor3=quad_perm(3,2,1,0)=0x1B; xor7=row_half_mirror=0x141;
//            xor15=row_mirror=0x140.

// v = Rot(phi,theta,omega) * RX(x) * |0>   (layer-1, unchanged/validated)
DEVINL void qubit_vec(float x, float phi, float theta, float omega,
                      float& v0r, float& v0i, float& v1r, float& v1i)
{
    float s, c;   fast_sincos_half(x, s, c);
    float st, ct; fast_sincos_half(theta, st, ct);
    float sa, ca; fast_sincos_half(phi + omega, sa, ca);
    float sb, cb; fast_sincos_half(phi - omega, sb, cb);
    const float A = c*ct, B = s*st, C = c*st, D = s*ct;
    v0r = ca*A - sb*B;
    v0i = cb*B - sa*A;
    v1r = cb*C + sa*D;
    v1i = -(sb*C + ca*D);
}

// RY pairing along register bit KM; amps with (k&KM)!=0 are "hi".
template<int KM>
DEVINL void ry_k(float (&ar)[16], float (&ai)[16], float c, float s) {
    #pragma unroll
    for (int k0 = 0; k0 < 16; ++k0) {
        if (k0 & KM) continue;
        const int k1 = k0 | KM;
        const float lr = ar[k0], li = ai[k0], hr = ar[k1], hi = ai[k1];
        ar[k0] = c*lr - s*hr;  ai[k0] = c*li - s*hi;
        ar[k1] = s*lr + c*hr;  ai[k1] = s*li + c*hi;
    }
}

// RY pairing along a DPP lane permutation; seff = hi ? +s : -s (per lane).
template<int CTRL>
DEVINL void ry_lane(float (&ar)[16], float (&ai)[16], float c, float seff) {
    #pragma unroll
    for (int k = 0; k < 16; ++k) {
        const float pr = dpp_perm<CTRL>(ar[k]);
        const float pi = dpp_perm<CTRL>(ai[k]);
        ar[k] = c*ar[k] + seff*pr;
        ai[k] = c*ai[k] + seff*pi;
    }
}

__global__ __launch_bounds__(256, 4)
void qcirc_kernel(const float* __restrict__ inputs,
                  const float* __restrict__ hidden,
                  float* __restrict__ out, int B)
{
    const int t  = threadIdx.x;
    const int e  = blockIdx.x * 16 + (t >> 4);
    const int sl = t & 15;
    if (e >= B) return;

    const int sl0 = sl & 1, sl1 = (sl >> 1) & 1, sl2 = (sl >> 2) & 1, sl3 = (sl >> 3) & 1;
    const int p01 = sl0 ^ sl1;

    // ---- loads: 8 inputs + 48 hidden ----
    float inv[8], hv[48];
    {
        const float4* ip = (const float4*)(inputs + (size_t)e * 8);
        ((float4*)inv)[0] = ip[0];
        ((float4*)inv)[1] = ip[1];
        const float4* hp = (const float4*)(hidden + (size_t)e * 48);
        #pragma unroll
        for (int j = 0; j < 12; ++j) ((float4*)hv)[j] = hp[j];
    }

    // ---- per-qubit 2-vectors (RX + layer-1 Rot) ----
    float vr[8][2], vi[8][2];
    #pragma unroll
    for (int q = 0; q < 8; ++q)
        qubit_vec(inv[q], hv[q*3], hv[q*3+1], hv[q*3+2],
                  vr[q][0], vi[q][0], vr[q][1], vi[q][1]);

    // ---- per-lane swapped vectors (mixed lane(+)k selectors) ----
    const float w0r0 = p01 ? vr[0][1] : vr[0][0], w0i0 = p01 ? vi[0][1] : vi[0][0];
    const float w0r1 = p01 ? vr[0][0] : vr[0][1], w0i1 = p01 ? vi[0][0] : vi[0][1];
    const float w1r0 = p01 ? vr[1][1] : vr[1][0], w1i0 = p01 ? vi[1][1] : vi[1][0];
    const float w1r1 = p01 ? vr[1][0] : vr[1][1], w1i1 = p01 ? vi[1][0] : vi[1][1];
    const float w4r0 = sl3 ? vr[4][1] : vr[4][0], w4i0 = sl3 ? vi[4][1] : vi[4][0];
    const float w4r1 = sl3 ? vr[4][0] : vr[4][1], w4i1 = sl3 ? vi[4][0] : vi[4][1];

    // ---- lane product L = v5[sl2] * v6[sl1^sl3] * v7[sl0^sl2] ----
    float Lr, Li;
    {
        const int s6 = sl1 ^ sl3, s7 = sl0 ^ sl2;
        const float ar5 = sl2 ? vr[5][1] : vr[5][0], ai5 = sl2 ? vi[5][1] : vi[5][0];
        const float ar6 = s6  ? vr[6][1] : vr[6][0], ai6 = s6  ? vi[6][1] : vi[6][0];
        const float ar7 = s7  ? vr[7][1] : vr[7][0], ai7 = s7  ? vi[7][1] : vi[7][0];
        float tr, ti;
        cmul(ar5, ai5, ar6, ai6, tr, ti);
        cmul(tr, ti, ar7, ai7, Lr, Li);
    }

    // ---- k-part trees ----
    // KA'[j=(k3<<1)|k2] = w0[k3]*w1[k3^k2]*L
    float KAr[4], KAi[4];
    #pragma unroll
    for (int j = 0; j < 4; ++j) {
        const int k3 = j >> 1, k2 = j & 1, x = k3 ^ k2;
        const float f0r = k3 ? w0r1 : w0r0, f0i = k3 ? w0i1 : w0i0;
        const float f1r = x  ? w1r1 : w1r0, f1i = x  ? w1i1 : w1i0;
        float tr, ti;
        cmul(f0r, f0i, f1r, f1i, tr, ti);
        cmul(tr, ti, Lr, Li, KAr[j], KAi[j]);
    }
    // KC[(k1<<1)|k0] = v3[k0^k1]*w4[k0];  K8[m=(k2k1k0)] = v2[k1^k2]*KC
    float KCr[4], KCi[4];
    #pragma unroll
    for (int m = 0; m < 4; ++m) {
        const int k1 = m >> 1, k0 = m & 1, x = k0 ^ k1;
        const float f4r = k0 ? w4r1 : w4r0, f4i = k0 ? w4i1 : w4i0;
        cmul(vr[3][x], vi[3][x], f4r, f4i, KCr[m], KCi[m]);
    }
    float K8r[8], K8i[8];
    #pragma unroll
    for (int m = 0; m < 8; ++m) {
        const int k2 = m >> 2, k1 = (m >> 1) & 1, x = k1 ^ k2;
        cmul(vr[2][x], vi[2][x], KCr[m & 3], KCi[m & 3], K8r[m], K8i[m]);
    }

    // ---- layer-2 phi phase diagonal (angles in revolutions) ----
    const float REV2 = 0.07957747154594767f;
    float h[8];
    #pragma unroll
    for (int p = 0; p < 8; ++p) h[p] = hv[24 + p*3] * REV2;
    const float lam = (sl3        ? h[4] : -h[4]) + ((sl3^sl2) ? h[5] : -h[5])
                    + ((sl2^sl1)  ? h[6] : -h[6]) + ((sl1^sl0) ? h[7] : -h[7]);
    float Aang[4];
    Aang[0] = lam - h[0] - h[1];
    Aang[1] = lam - h[0] + h[1];
    Aang[2] = lam + h[0] - h[1];
    Aang[3] = lam + h[0] + h[1];
    const float Bs = h[2] + h[3], Bd = h[2] - h[3];

    // ---- init state = product * phase diagonal ----
    float ar[16], ai[16];
    #pragma unroll
    for (int k = 0; k < 16; ++k) {
        const int j = k >> 2, m = k & 7, mm = k & 3;
        const float ang = Aang[j] + (mm == 0 ? -Bs : mm == 1 ? -Bd : mm == 2 ? Bd : Bs);
        const float cr = __builtin_amdgcn_cosf(ang);
        const float ci = __builtin_amdgcn_sinf(ang);
        float tr, ti;
        cmul(KAr[j], KAi[j], K8r[m], K8i[m], tr, ti);
        cmul(tr, ti, cr, ci, ar[k], ai[k]);
    }

    // ---- layer-2 RY gates ----
    float s2[8], c2[8];
    #pragma unroll
    for (int p = 0; p < 8; ++p) fast_sincos_half(hv[24 + p*3 + 1], s2[p], c2[p]);

    ry_k<8>(ar, ai, c2[0], s2[0]);    // q0: k3
    ry_k<4>(ar, ai, c2[1], s2[1]);    // q1: k2
    ry_k<2>(ar, ai, c2[2], s2[2]);    // q2: k1
    ry_k<1>(ar, ai, c2[3], s2[3]);    // q3: k0

    const float e4 = sl3        ? s2[4] : -s2[4];
    const float e5 = (sl3^sl2)  ? s2[5] : -s2[5];
    const float e6 = (sl2^sl1)  ? s2[6] : -s2[6];
    const float e7 = (sl1^sl0)  ? s2[7] : -s2[7];
    ry_lane<0x140>(ar, ai, c2[4], e4);   // q4: lane xor15 (row_mirror)
    ry_lane<0x141>(ar, ai, c2[5], e5);   // q5: lane xor7  (row_half_mirror)
    ry_lane<0x1B> (ar, ai, c2[6], e6);   // q6: lane xor3  (quad rev)
    ry_lane<0xB1> (ar, ai, c2[7], e7);   // q7: lane xor1  (quad swap)

    // ---- Z expectations: k-part Walsh (masks 7,C,E,F) ----
    float P[16];
    #pragma unroll
    for (int k = 0; k < 16; ++k) P[k] = ar[k]*ar[k] + ai[k]*ai[k];

    float S0[4], S1[4], S3[4];
    #pragma unroll
    for (int j = 0; j < 4; ++j) {
        const float p00 = P[j*4+0], p01v = P[j*4+1], p10 = P[j*4+2], p11 = P[j*4+3];
        const float u = p00 + p01v, w = p10 + p11;
        const float d0 = p00 - p01v, d1 = p10 - p11;
        S0[j] = u + w;      // no (k1,k0) sign
        S1[j] = u - w;      // (-1)^{k1}
        S3[j] = d0 - d1;    // (-1)^{k1+k0}
    }
    float VC = S0[0] - S0[1] - S0[2] + S0[3];   // mask C: (-1)^{k3+k2}
    float VE = S1[0] - S1[1] - S1[2] + S1[3];   // mask E
    float VF = S3[0] - S3[1] - S3[2] + S3[3];   // mask F
    float V7 = S3[0] - S3[1] + S3[2] - S3[3];   // mask 7: (-1)^{k2} outer

    // ---- FWHT over 4 lane bits (xor1,2 via DPP; xor4,8 via shfl) ----
    {
        const float g1 = (sl & 1) ? -1.f : 1.f;
        V7 = fmaf(g1, V7, dpp_perm<0xB1>(V7));
        VC = fmaf(g1, VC, dpp_perm<0xB1>(VC));
        VE = fmaf(g1, VE, dpp_perm<0xB1>(VE));
        VF = fmaf(g1, VF, dpp_perm<0xB1>(VF));
        const float g2 = (sl & 2) ? -1.f : 1.f;
        V7 = fmaf(g2, V7, dpp_perm<0x4E>(V7));
        VC = fmaf(g2, VC, dpp_perm<0x4E>(VC));
        VE = fmaf(g2, VE, dpp_perm<0x4E>(VE));
        VF = fmaf(g2, VF, dpp_perm<0x4E>(VF));
        const float g4 = (sl & 4) ? -1.f : 1.f;
        V7 = fmaf(g4, V7, __shfl_xor(V7, 4, 64));
        VC = fmaf(g4, VC, __shfl_xor(VC, 4, 64));
        VE = fmaf(g4, VE, __shfl_xor(VE, 4, 64));
        VF = fmaf(g4, VF, __shfl_xor(VF, 4, 64));
        const float g8 = (sl & 8) ? -1.f : 1.f;
        V7 = fmaf(g8, V7, __shfl_xor(V7, 8, 64));
        VC = fmaf(g8, VC, __shfl_xor(VC, 8, 64));
        VE = fmaf(g8, VE, __shfl_xor(VE, 8, 64));
        VF = fmaf(g8, VF, __shfl_xor(VF, 8, 64));
    }

    // ---- gather one result per lane 0..7, tanh, coalesced store ----
    // q0<-V7@l1  q1<-VC@l0  q2<-VE@l0  q3<-VF@l0  q4..q7<-VF@l{8,4,2,1}
    const int gb = (t & 63) & 48;
    const float B7 = __shfl(V7, gb + 1, 64);
    const float BC = __shfl(VC, gb, 64);
    const float BE = __shfl(VE, gb, 64);
    const int fidx = (sl >= 4) ? (128 >> sl) : 0;
    const float BF = __shfl(VF, gb + fidx, 64);
    const float rsel = (sl == 0) ? B7 : (sl == 1) ? BC : (sl == 2) ? BE : BF;
    const float hres = fast_tanh(rsel);
    if (sl < 8) {
        const size_t obase = (size_t)e * 8;
        const size_t half  = (size_t)B * 8;
        out[obase + sl]        = hres;
        out[half + obase + sl] = hres;
    }
}

extern "C" void kernel_launch(void* const* d_in, const int* in_sizes, int n_in,
                              void* d_out, int out_size, void* d_ws, size_t ws_size,
                              hipStream_t stream)
{
    const float* inputs = (const float*)d_in[0];   // (B, 8) fp32
    const float* hidden = (const float*)d_in[1];   // (B, 2, 1, 8, 3) fp32
    float* out = (float*)d_out;                    // (2, B, 8) fp32 (tuple (h,h))
    const int B = in_sizes[0] / 8;                 // 16384
    const int blocks = (B + 15) / 16;              // 16 lanes per element
    hipLaunchKernelGGL(qcirc_kernel, dim3(blocks), dim3(256), 0, stream,
                       inputs, hidden, out, B);
}

// Round 6
// 14.934 us; speedup vs baseline: 4.9672x; 1.0494x over previous
//
#include <hip/hip_runtime.h>
#include <math.h>

// 8-qubit statevector sim, TWO elements per 64-lane wave (32 lanes each).
// Storage index z' (8 bits): z'0-4 = lane-in-group sl (5 bits), z'5-7 = reg k
// (k0=z'5, k1=z'6, k2=z'7). Derived from the round-5 VALIDATED layout by an
// explicit GF(2) relabeling M (e0->01, e1->03, e2->05, e3->0F, e4..7 identity),
// with every mask/selector transformed by substitution (checked twice):
//   z0=z'0^z'1^z'2^z'3, z1=z'1^z'3, z2=z'2^z'3, z3=z'3, z4..7=z'4..7.
// Layer-2 RY pair masks:  q0:k2  q1:k1  q2:k0  q3:lane xor16  q4:xor8(DPP
//   row_ror:8) q5:xor7(half_mirror) q6:xor2(quad) q7:xor1(quad)
// Layer-2 selectors (hi): q0:k2 q1:k1 q2:k0 q3:sl4 q4:sl3 q5:sl2
//   q6:sl1^sl2 q7:sl0^sl2   (phase diagonal uses same selectors: +h iff sel)
// Product selectors: q0:sl0^sl2^k2  q1:sl0^sl2^k1^k2  q2:k0^k1  q3:sl4^k0
//   q4:sl3^sl4  q5:sl2^sl3  q6:sl1  q7:sl0^sl1
// Z-measure Walsh masks: k-parts q0:3 q1:6 q2..7:7; lane parts
//   q0:31 q1:0 q2:0 q3:16 q4:24 q5:28 q6:26 q7:31.
// Scalar phase is DISTRIBUTED: lane (sl&7) owns qubit (sl&7) - loads its 6
// angles, computes its qubit_vec + layer-2 trig; values shared via bpermute.

#define DEVINL __device__ __forceinline__

DEVINL void fast_sincos_half(float x, float& s, float& c) {
    const float r = x * 0.07957747154594767f;   // (x/2)/(2*pi): HW trig in revolutions
    s = __builtin_amdgcn_sinf(r);
    c = __builtin_amdgcn_cosf(r);
}

DEVINL float fast_tanh(float x) {
    const float t = __builtin_amdgcn_exp2f(x * 2.8853900817779268f);  // e^{2x}
    return 1.0f - 2.0f * __builtin_amdgcn_rcpf(t + 1.0f);
}

DEVINL void cmul(float ar, float ai, float br, float bi, float& cr, float& ci) {
    cr = ar*br - ai*bi;
    ci = ar*bi + ai*br;
}
// conj(a) * b
DEVINL void cmulc(float ar, float ai, float br, float bi, float& cr, float& ci) {
    cr = ar*br + ai*bi;
    ci = ar*bi - ai*br;
}

template<int CTRL>
DEVINL float dpp_perm(float x) {
    return __int_as_float(__builtin_amdgcn_update_dpp(
        __float_as_int(x), __float_as_int(x), CTRL, 0xF, 0xF, false));
}
// ctrls: xor1=0xB1 (quad 1,0,3,2); xor2=0x4E (quad 2,3,0,1);
//        xor7=0x141 (row_half_mirror); xor8=0x128 (row_ror:8).

// v = Rot(phi,theta,omega) * RX(x) * |0>   (layer-1, validated rounds 3-5)
DEVINL void qubit_vec(float x, float phi, float theta, float omega,
                      float& v0r, float& v0i, float& v1r, float& v1i)
{
    float s, c;   fast_sincos_half(x, s, c);
    float st, ct; fast_sincos_half(theta, st, ct);
    float sa, ca; fast_sincos_half(phi + omega, sa, ca);
    float sb, cb; fast_sincos_half(phi - omega, sb, cb);
    const float A = c*ct, B = s*st, C = c*st, D = s*ct;
    v0r = ca*A - sb*B;
    v0i = cb*B - sa*A;
    v1r = cb*C + sa*D;
    v1i = -(sb*C + ca*D);
}

// RY on register bit KM (selector == pairing bit): hi regs have (k&KM)!=0.
template<int KM>
DEVINL void ry_k8(float (&ar)[8], float (&ai)[8], float c, float s) {
    #pragma unroll
    for (int k0 = 0; k0 < 8; ++k0) {
        if (k0 & KM) continue;
        const int k1 = k0 | KM;
        const float lr = ar[k0], li = ai[k0], hr = ar[k1], hi = ai[k1];
        ar[k0] = c*lr - s*hr;  ai[k0] = c*li - s*hi;
        ar[k1] = s*lr + c*hr;  ai[k1] = s*li + c*hi;
    }
}

// RY on a DPP lane permutation; seff = hi-lane ? +s : -s.
template<int CTRL>
DEVINL void ry_lane8(float (&ar)[8], float (&ai)[8], float c, float seff) {
    #pragma unroll
    for (int k = 0; k < 8; ++k) {
        const float pr = dpp_perm<CTRL>(ar[k]);
        const float pi = dpp_perm<CTRL>(ai[k]);
        ar[k] = c*ar[k] + seff*pr;
        ai[k] = c*ai[k] + seff*pi;
    }
}

DEVINL void ry_xor16(float (&ar)[8], float (&ai)[8], float c, float seff) {
    #pragma unroll
    for (int k = 0; k < 8; ++k) {
        const float pr = __shfl_xor(ar[k], 16, 64);
        const float pi = __shfl_xor(ai[k], 16, 64);
        ar[k] = c*ar[k] + seff*pr;
        ai[k] = c*ai[k] + seff*pi;
    }
}

__global__ __launch_bounds__(256, 8)
void qcirc_kernel(const float* __restrict__ inputs,
                  const float* __restrict__ hidden,
                  float* __restrict__ out, int B)
{
    const int t  = threadIdx.x;
    const int e  = blockIdx.x * 8 + (t >> 5);
    if (e >= B) return;
    const int sl = t & 31;
    const int gb = t & 32;                 // wave-relative 32-group base
    const int q  = sl & 7;                 // owned qubit
    const int sl0 = sl & 1, sl1 = (sl >> 1) & 1, sl2 = (sl >> 2) & 1,
              sl3 = (sl >> 3) & 1, sl4 = (sl >> 4) & 1;

    // ---- owner loads: only this lane's qubit's angles ----
    const float  x   = inputs[(size_t)e * 8 + q];
    const float* hb  = hidden + (size_t)e * 48 + q * 3;
    const float ph1 = hb[0], th1 = hb[1], om1 = hb[2];
    const float ph2 = hb[24], th2 = hb[25];        // layer-2 phi, theta (omega cancels)

    // ---- owner compute: qubit_vec + layer-2 trig ----
    float ov0r, ov0i, ov1r, ov1i;
    qubit_vec(x, ph1, th1, om1, ov0r, ov0i, ov1r, ov1i);
    float s2o, c2o; fast_sincos_half(th2, s2o, c2o);
    const float ho  = ph2 * 0.07957747154594767f;  // phi2/2 in revolutions
    const float Eco = __builtin_amdgcn_cosf(ho);
    const float Eso = __builtin_amdgcn_sinf(ho);

    // ---- broadcast q4..q7 vectors, fold into lane product L ----
    float Lr, Li;
    {
        float fr[4][2], fi[4][2];
        #pragma unroll
        for (int p = 0; p < 4; ++p) {
            fr[p][0] = __shfl(ov0r, gb + 4 + p, 64);
            fi[p][0] = __shfl(ov0i, gb + 4 + p, 64);
            fr[p][1] = __shfl(ov1r, gb + 4 + p, 64);
            fi[p][1] = __shfl(ov1i, gb + 4 + p, 64);
        }
        const int s4 = sl3 ^ sl4, s5 = sl2 ^ sl3, s6 = sl1, s7 = sl0 ^ sl1;
        const float a4r = s4 ? fr[0][1] : fr[0][0], a4i = s4 ? fi[0][1] : fi[0][0];
        const float a5r = s5 ? fr[1][1] : fr[1][0], a5i = s5 ? fi[1][1] : fi[1][0];
        const float a6r = s6 ? fr[2][1] : fr[2][0], a6i = s6 ? fi[2][1] : fi[2][0];
        const float a7r = s7 ? fr[3][1] : fr[3][0], a7i = s7 ? fi[3][1] : fi[3][0];
        float tr, ti;
        cmul(a4r, a4i, a5r, a5i, tr, ti);
        cmul(tr, ti, a6r, a6i, Lr, Li);
        cmul(Lr, Li, a7r, a7i, tr, ti);
        Lr = tr; Li = ti;
    }

    // ---- fetch phase scalars; apply lam phase to L ----
    const float E0c = __shfl(Eco, gb + 0, 64), E0s = __shfl(Eso, gb + 0, 64);
    const float E1c = __shfl(Eco, gb + 1, 64), E1s = __shfl(Eso, gb + 1, 64);
    const float E2c = __shfl(Eco, gb + 2, 64), E2s = __shfl(Eso, gb + 2, 64);
    {
        const float h3 = __shfl(ho, gb + 3, 64);
        const float h4 = __shfl(ho, gb + 4, 64);
        const float h5 = __shfl(ho, gb + 5, 64);
        const float h6 = __shfl(ho, gb + 6, 64);
        const float h7 = __shfl(ho, gb + 7, 64);
        const float lam = (sl4 ? h3 : -h3) + (sl3 ? h4 : -h4) + (sl2 ? h5 : -h5)
                        + ((sl1 ^ sl2) ? h6 : -h6) + ((sl0 ^ sl2) ? h7 : -h7);
        const float Pc = __builtin_amdgcn_cosf(lam);
        const float Ps = __builtin_amdgcn_sinf(lam);
        float tr, ti; cmul(Lr, Li, Pc, Ps, tr, ti);
        Lr = tr; Li = ti;
    }

    // ---- broadcast q0..q3 vectors ----
    float vr[4][2], vi[4][2];
    #pragma unroll
    for (int p = 0; p < 4; ++p) {
        vr[p][0] = __shfl(ov0r, gb + p, 64);
        vi[p][0] = __shfl(ov0i, gb + p, 64);
        vr[p][1] = __shfl(ov1r, gb + p, 64);
        vi[p][1] = __shfl(ov1i, gb + p, 64);
    }

    // ---- pre-swapped vectors for mixed lane(+)k selectors ----
    const int b01 = sl0 ^ sl2;
    const float w0r0 = b01 ? vr[0][1] : vr[0][0], w0i0 = b01 ? vi[0][1] : vi[0][0];
    const float w0r1 = b01 ? vr[0][0] : vr[0][1], w0i1 = b01 ? vi[0][0] : vi[0][1];
    const float w1r0 = b01 ? vr[1][1] : vr[1][0], w1i0 = b01 ? vi[1][1] : vi[1][0];
    const float w1r1 = b01 ? vr[1][0] : vr[1][1], w1i1 = b01 ? vi[1][0] : vi[1][1];
    const float w3r0 = sl4 ? vr[3][1] : vr[3][0], w3i0 = sl4 ? vi[3][1] : vi[3][0];
    const float w3r1 = sl4 ? vr[3][0] : vr[3][1], w3i1 = sl4 ? vi[3][0] : vi[3][1];

    // w3ph[j] = w3[j] * E2^{+1 if j else -1}   (phase of q2, selector k0)
    float w3p0r, w3p0i, w3p1r, w3p1i;
    cmulc(E2c, E2s, w3r0, w3i0, w3p0r, w3p0i);
    cmul (w3r1, w3i1, E2c, E2s, w3p1r, w3p1i);

    // G[(k2,k1)] = E0^{+-k2} E1^{+-k1}; GL = G * L
    float GL0r, GL0i, GL1r, GL1i, GL2r, GL2i, GL3r, GL3i;
    {
        const float a = E0c*E1c, b = E0s*E1s, c = E0c*E1s, d = E0s*E1c;
        const float P3r = a - b, P3i = c + d;   // E0*E1
        const float P1r = a + b, P1i = c - d;   // conj(E0)*E1
        cmulc(P3r, P3i, Lr, Li, GL0r, GL0i);    // conj(P3)*L
        cmul (P1r, P1i, Lr, Li, GL1r, GL1i);
        cmulc(P1r, P1i, Lr, Li, GL2r, GL2i);    // conj(P1)*L
        cmul (P3r, P3i, Lr, Li, GL3r, GL3i);
    }

    // T2L[(k2,k1)] = w0[k2] * w1[k1^k2] * GL ;  T1[(k1,k0)] = v2[k0^k1]*w3ph[k0]
    float T2r[4], T2i[4], T1r[4], T1i[4];
    {
        float tr, ti;
        cmul(w0r0, w0i0, w1r0, w1i0, tr, ti); cmul(tr, ti, GL0r, GL0i, T2r[0], T2i[0]);
        cmul(w0r0, w0i0, w1r1, w1i1, tr, ti); cmul(tr, ti, GL1r, GL1i, T2r[1], T2i[1]);
        cmul(w0r1, w0i1, w1r1, w1i1, tr, ti); cmul(tr, ti, GL2r, GL2i, T2r[2], T2i[2]);
        cmul(w0r1, w0i1, w1r0, w1i0, tr, ti); cmul(tr, ti, GL3r, GL3i, T2r[3], T2i[3]);
        cmul(vr[2][0], vi[2][0], w3p0r, w3p0i, T1r[0], T1i[0]);
        cmul(vr[2][1], vi[2][1], w3p1r, w3p1i, T1r[1], T1i[1]);
        cmul(vr[2][1], vi[2][1], w3p0r, w3p0i, T1r[2], T1i[2]);
        cmul(vr[2][0], vi[2][0], w3p1r, w3p1i, T1r[3], T1i[3]);
    }

    // ---- init state: amp[k] = T2L[k>>1] * T1[k&3] ----
    float ar[8], ai[8];
    #pragma unroll
    for (int k = 0; k < 8; ++k) {
        cmul(T2r[k >> 1], T2i[k >> 1], T1r[k & 3], T1i[k & 3], ar[k], ai[k]);
    }

    // ---- layer-2 RY gates (c,s fetched from owner lanes) ----
    { const float c = __shfl(c2o, gb + 0, 64), s = __shfl(s2o, gb + 0, 64);
      ry_k8<4>(ar, ai, c, s); }                                   // q0: k2
    { const float c = __shfl(c2o, gb + 1, 64), s = __shfl(s2o, gb + 1, 64);
      ry_k8<2>(ar, ai, c, s); }                                   // q1: k1
    { const float c = __shfl(c2o, gb + 2, 64), s = __shfl(s2o, gb + 2, 64);
      ry_k8<1>(ar, ai, c, s); }                                   // q2: k0
    { const float c = __shfl(c2o, gb + 3, 64), s = __shfl(s2o, gb + 3, 64);
      ry_xor16(ar, ai, c, sl4 ? s : -s); }                        // q3: lane xor16
    { const float c = __shfl(c2o, gb + 4, 64), s = __shfl(s2o, gb + 4, 64);
      ry_lane8<0x128>(ar, ai, c, sl3 ? s : -s); }                 // q4: xor8
    { const float c = __shfl(c2o, gb + 5, 64), s = __shfl(s2o, gb + 5, 64);
      ry_lane8<0x141>(ar, ai, c, sl2 ? s : -s); }                 // q5: xor7
    { const float c = __shfl(c2o, gb + 6, 64), s = __shfl(s2o, gb + 6, 64);
      ry_lane8<0x4E>(ar, ai, c, (sl1 ^ sl2) ? s : -s); }          // q6: xor2
    { const float c = __shfl(c2o, gb + 7, 64), s = __shfl(s2o, gb + 7, 64);
      ry_lane8<0xB1>(ar, ai, c, (sl0 ^ sl2) ? s : -s); }          // q7: xor1

    // ---- Z expectations: k-part Walsh (masks 3,6,7) ----
    float P[8];
    #pragma unroll
    for (int k = 0; k < 8; ++k) P[k] = ar[k]*ar[k] + ai[k]*ai[k];
    const float u0 = P[0]+P[1], v0 = P[0]-P[1];
    const float u1 = P[2]+P[3], v1 = P[2]-P[3];
    const float u2 = P[4]+P[5], v2 = P[4]-P[5];
    const float u3 = P[6]+P[7], v3 = P[6]-P[7];
    float V3 = v0 - v1 + v2 - v3;    // (-1)^{k1+k0}
    float V6 = u0 - u1 - u2 + u3;    // (-1)^{k2+k1}
    float V7 = v0 - v1 - v2 + v3;    // (-1)^{k2+k1+k0}

    // ---- FWHT over 5 lane bits (xor1,2,8 via DPP; xor4,16 via shfl) ----
    {
        const float g1 = (sl & 1) ? -1.f : 1.f;
        V3 = fmaf(g1, V3, dpp_perm<0xB1>(V3));
        V6 = fmaf(g1, V6, dpp_perm<0xB1>(V6));
        V7 = fmaf(g1, V7, dpp_perm<0xB1>(V7));
        const float g2 = (sl & 2) ? -1.f : 1.f;
        V3 = fmaf(g2, V3, dpp_perm<0x4E>(V3));
        V6 = fmaf(g2, V6, dpp_perm<0x4E>(V6));
        V7 = fmaf(g2, V7, dpp_perm<0x4E>(V7));
        const float g4 = (sl & 4) ? -1.f : 1.f;
        V3 = fmaf(g4, V3, __shfl_xor(V3, 4, 64));
        V6 = fmaf(g4, V6, __shfl_xor(V6, 4, 64));
        V7 = fmaf(g4, V7, __shfl_xor(V7, 4, 64));
        const float g8 = (sl & 8) ? -1.f : 1.f;
        V3 = fmaf(g8, V3, dpp_perm<0x128>(V3));
        V6 = fmaf(g8, V6, dpp_perm<0x128>(V6));
        V7 = fmaf(g8, V7, dpp_perm<0x128>(V7));
        const float g16 = (sl & 16) ? -1.f : 1.f;
        V3 = fmaf(g16, V3, __shfl_xor(V3, 16, 64));
        V6 = fmaf(g16, V6, __shfl_xor(V6, 16, 64));
        V7 = fmaf(g16, V7, __shfl_xor(V7, 16, 64));
    }

    // ---- gather per-qubit results, tanh, store ----
    // q0: V3@31  q1: V6@0  q2: V7@0  q3: V7@16  q4: V7@24  q5: V7@28
    // q6: V7@26  q7: V7@31
    const int idx7 = (sl == 3) ? 16 : (sl == 4) ? 24 : (sl == 5) ? 28
                   : (sl == 6) ? 26 : (sl == 7) ? 31 : 0;
    const float B3 = __shfl(V3, gb + 31, 64);
    const float B6 = __shfl(V6, gb + 0, 64);
    const float B7 = __shfl(V7, gb + idx7, 64);
    const float rsel = (sl == 0) ? B3 : (sl == 1) ? B6 : B7;
    const float h = fast_tanh(rsel);
    if (sl < 8) {
        const size_t obase = (size_t)e * 8;
        out[obase + sl] = h;
        out[(size_t)B * 8 + obase + sl] = h;
    }
}

extern "C" void kernel_launch(void* const* d_in, const int* in_sizes, int n_in,
                              void* d_out, int out_size, void* d_ws, size_t ws_size,
                              hipStream_t stream)
{
    const float* inputs = (const float*)d_in[0];   // (B, 8) fp32
    const float* hidden = (const float*)d_in[1];   // (B, 2, 1, 8, 3) fp32
    float* out = (float*)d_out;                    // (2, B, 8) fp32 (tuple (h,h))
    const int B = in_sizes[0] / 8;                 // 16384
    const int blocks = (B + 7) / 8;                // 32 lanes per element
    hipLaunchKernelGGL(qcirc_kernel, dim3(blocks), dim3(256), 0, stream,
                       inputs, hidden, out, B);
}

// Round 7
// 13.528 us; speedup vs baseline: 5.4835x; 1.1039x over previous
//
#include <hip/hip_runtime.h>
#include <math.h>

// 8-qubit statevector sim, TWO elements per 64-lane wave (32 lanes each).
// Layout and ALL masks/selectors identical to the validated round-6 kernel:
//   z'0-4 = lane sl, z'5-7 = reg k (k0=z'5,k1=z'6,k2=z'7).
//   Layer-2 RY masks: q0:k2 q1:k1 q2:k0 q3:xor16 q4:xor8 q5:xor7 q6:xor2 q7:xor1
//   Selectors: q0:k2 q1:k1 q2:k0 q3:sl4 q4:sl3 q5:sl2 q6:sl1^sl2 q7:sl0^sl2
//   Product selectors: q0:sl0^sl2^k2 q1:sl0^sl2^k1^k2 q2:k0^k1 q3:sl4^k0
//     q4:sl3^sl4 q5:sl2^sl3 q6:sl1 q7:sl0^sl1
//   Z Walsh masks: k-parts q0:3 q1:6 else 7; lane picks q0:31 q1:0 q2:0
//     q3:16 q4:24 q5:28 q6:26 q7:31.
// NEW this round (mechanics only, same math):
//  - scalar sharing via a per-element LDS table (owner lanes sl<8 write one
//    32B record per qubit; same-wave consumers ds_read at const offsets; no
//    barrier needed - intra-wave lgkmcnt ordering).
//  - q0's RY folded into the T2 tree (k2 lives only there), q2's RY into T1
//    (k0 lives only there); q1 (k1 straddles both trees) stays on full amps.
//  - ds_swizzle for xor16 / xor4 / lane broadcasts.

#define DEVINL __device__ __forceinline__

DEVINL void fast_sincos_half(float x, float& s, float& c) {
    const float r = x * 0.07957747154594767f;   // (x/2)/(2*pi): HW trig in revolutions
    s = __builtin_amdgcn_sinf(r);
    c = __builtin_amdgcn_cosf(r);
}

DEVINL float fast_tanh(float x) {
    const float t = __builtin_amdgcn_exp2f(x * 2.8853900817779268f);  // e^{2x}
    return 1.0f - 2.0f * __builtin_amdgcn_rcpf(t + 1.0f);
}

DEVINL void cmul(float ar, float ai, float br, float bi, float& cr, float& ci) {
    cr = ar*br - ai*bi;
    ci = ar*bi + ai*br;
}
// conj(a) * b
DEVINL void cmulc(float ar, float ai, float br, float bi, float& cr, float& ci) {
    cr = ar*br + ai*bi;
    ci = ar*bi - ai*br;
}

template<int CTRL>
DEVINL float dpp_perm(float x) {
    return __int_as_float(__builtin_amdgcn_update_dpp(
        __float_as_int(x), __float_as_int(x), CTRL, 0xF, 0xF, false));
}
// DPP ctrls: xor1=0xB1 (quad 1,0,3,2); xor2=0x4E (quad 2,3,0,1);
//            xor7=0x141 (row_half_mirror); xor8=0x128 (row_ror:8).

template<int OFF>
DEVINL float swz(float x) {
    return __int_as_float(__builtin_amdgcn_ds_swizzle(__float_as_int(x), OFF));
}
// BitMode offset = (xor<<10)|(or<<5)|and, per 32-lane half:
//   xor16 = 0x401F; xor4 = 0x101F; bcast lane31 = 0x3E0; bcast lane0 = 0x000.

// v = Rot(phi,theta,omega) * RX(x) * |0>   (layer-1, validated rounds 3-6)
DEVINL void qubit_vec(float x, float phi, float theta, float omega,
                      float& v0r, float& v0i, float& v1r, float& v1i)
{
    float s, c;   fast_sincos_half(x, s, c);
    float st, ct; fast_sincos_half(theta, st, ct);
    float sa, ca; fast_sincos_half(phi + omega, sa, ca);
    float sb, cb; fast_sincos_half(phi - omega, sb, cb);
    const float A = c*ct, B = s*st, C = c*st, D = s*ct;
    v0r = ca*A - sb*B;
    v0i = cb*B - sa*A;
    v1r = cb*C + sa*D;
    v1i = -(sb*C + ca*D);
}

__global__ __launch_bounds__(256, 8)
void qcirc_kernel(const float* __restrict__ inputs,
                  const float* __restrict__ hidden,
                  float* __restrict__ out, int B)
{
    __shared__ __align__(16) float lds[512];   // 8 elements x 8 qubits x 8 floats

    const int t  = threadIdx.x;
    const int e  = blockIdx.x * 8 + (t >> 5);
    if (e >= B) return;
    const int sl = t & 31;
    const int gb = t & 32;                 // wave-half base (for the one bpermute)
    const int q  = sl & 7;                 // owned qubit
    const int eb = (t >> 5) * 64;          // element base in LDS (floats)
    const int sl0 = sl & 1, sl1 = (sl >> 1) & 1, sl2 = (sl >> 2) & 1,
              sl3 = (sl >> 3) & 1, sl4 = (sl >> 4) & 1;

    // ---- owner compute (4x redundant across replicas; lanes sl<8 write) ----
    const float  x  = inputs[(size_t)e * 8 + q];
    const float* hb = hidden + (size_t)e * 48 + q * 3;
    const float ph1 = hb[0], th1 = hb[1], om1 = hb[2];
    const float ph2 = hb[24], th2 = hb[25];        // layer-2 omega cancels

    float ov0r, ov0i, ov1r, ov1i;
    qubit_vec(x, ph1, th1, om1, ov0r, ov0i, ov1r, ov1i);
    float s2o, c2o; fast_sincos_half(th2, s2o, c2o);
    const float ho = ph2 * 0.07957747154594767f;   // phi2/2 in revolutions
    const float Ec = __builtin_amdgcn_cosf(ho);
    const float Es = __builtin_amdgcn_sinf(ho);
    const float Av = (q < 3) ? Ec : ho;            // q<3 store E=(cos,sin); else raw h
    const float Bv = (q < 3) ? Es : 0.f;

    if (sl < 8) {
        *(float4*)(lds + eb + q*8)     = make_float4(ov0r, ov0i, ov1r, ov1i);
        *(float4*)(lds + eb + q*8 + 4) = make_float4(c2o, s2o, Av, Bv);
    }
    // producer and consumers are the SAME wave: lgkmcnt ordering suffices.

    // ---- lane product L over q4..q7 ----
    const float4 r4v = *(const float4*)(lds + eb + 32);
    const float4 r5v = *(const float4*)(lds + eb + 40);
    const float4 r6v = *(const float4*)(lds + eb + 48);
    const float4 r7v = *(const float4*)(lds + eb + 56);
    const int s4 = sl3 ^ sl4, s5 = sl2 ^ sl3, s6 = sl1, s7 = sl0 ^ sl1;
    const float a4r = s4 ? r4v.z : r4v.x, a4i = s4 ? r4v.w : r4v.y;
    const float a5r = s5 ? r5v.z : r5v.x, a5i = s5 ? r5v.w : r5v.y;
    const float a6r = s6 ? r6v.z : r6v.x, a6i = s6 ? r6v.w : r6v.y;
    const float a7r = s7 ? r7v.z : r7v.x, a7i = s7 ? r7v.w : r7v.y;
    float Lr, Li, tr, ti;
    cmul(a4r, a4i, a5r, a5i, tr, ti);
    cmul(tr, ti, a6r, a6i, Lr, Li);
    cmul(Lr, Li, a7r, a7i, tr, ti); Lr = tr; Li = ti;

    // ---- lam phase on L (raw h of q3..q7) ----
    {
        const float h3 = lds[eb + 3*8 + 6];
        const float h4 = lds[eb + 4*8 + 6];
        const float h5 = lds[eb + 5*8 + 6];
        const float h6 = lds[eb + 6*8 + 6];
        const float h7 = lds[eb + 7*8 + 6];
        const float lam = (sl4 ? h3 : -h3) + (sl3 ? h4 : -h4) + (sl2 ? h5 : -h5)
                        + ((sl1 ^ sl2) ? h6 : -h6) + ((sl0 ^ sl2) ? h7 : -h7);
        const float Pc = __builtin_amdgcn_cosf(lam);
        const float Ps = __builtin_amdgcn_sinf(lam);
        cmul(Lr, Li, Pc, Ps, tr, ti); Lr = tr; Li = ti;
    }

    // ---- phase exponentials of q0..q2 (precomputed by owners) ----
    const float2 E0 = *(const float2*)(lds + eb + 0*8 + 6);
    const float2 E1 = *(const float2*)(lds + eb + 1*8 + 6);
    const float2 E2 = *(const float2*)(lds + eb + 2*8 + 6);

    // ---- q0..q3 vectors ----
    const float4 r0v = *(const float4*)(lds + eb + 0);
    const float4 r1v = *(const float4*)(lds + eb + 8);
    const float4 r2v = *(const float4*)(lds + eb + 16);
    const float4 r3v = *(const float4*)(lds + eb + 24);

    const int b01 = sl0 ^ sl2;
    const float w0r0 = b01 ? r0v.z : r0v.x, w0i0 = b01 ? r0v.w : r0v.y;
    const float w0r1 = b01 ? r0v.x : r0v.z, w0i1 = b01 ? r0v.y : r0v.w;
    const float w1r0 = b01 ? r1v.z : r1v.x, w1i0 = b01 ? r1v.w : r1v.y;
    const float w1r1 = b01 ? r1v.x : r1v.z, w1i1 = b01 ? r1v.y : r1v.w;
    const float w3r0 = sl4 ? r3v.z : r3v.x, w3i0 = sl4 ? r3v.w : r3v.y;
    const float w3r1 = sl4 ? r3v.x : r3v.z, w3i1 = sl4 ? r3v.y : r3v.w;

    // w3ph[j] = w3[j] * E2^{+1 if j else -1}
    float w3p0r, w3p0i, w3p1r, w3p1i;
    cmulc(E2.x, E2.y, w3r0, w3i0, w3p0r, w3p0i);
    cmul (w3r1, w3i1, E2.x, E2.y, w3p1r, w3p1i);

    // GL[(k2,k1)] = E0^{+-} E1^{+-} * L
    float GL0r, GL0i, GL1r, GL1i, GL2r, GL2i, GL3r, GL3i;
    {
        const float a = E0.x*E1.x, b2 = E0.y*E1.y, c = E0.x*E1.y, d = E0.y*E1.x;
        const float P3r = a - b2, P3i = c + d;   // E0*E1
        const float P1r = a + b2, P1i = c - d;   // conj(E0)*E1
        cmulc(P3r, P3i, Lr, Li, GL0r, GL0i);
        cmul (P1r, P1i, Lr, Li, GL1r, GL1i);
        cmulc(P1r, P1i, Lr, Li, GL2r, GL2i);
        cmul (P3r, P3i, Lr, Li, GL3r, GL3i);
    }

    // ---- trees ----
    float T2r[4], T2i[4], T1r[4], T1i[4];
    cmul(w0r0, w0i0, w1r0, w1i0, tr, ti); cmul(tr, ti, GL0r, GL0i, T2r[0], T2i[0]);
    cmul(w0r0, w0i0, w1r1, w1i1, tr, ti); cmul(tr, ti, GL1r, GL1i, T2r[1], T2i[1]);
    cmul(w0r1, w0i1, w1r1, w1i1, tr, ti); cmul(tr, ti, GL2r, GL2i, T2r[2], T2i[2]);
    cmul(w0r1, w0i1, w1r0, w1i0, tr, ti); cmul(tr, ti, GL3r, GL3i, T2r[3], T2i[3]);
    cmul(r2v.x, r2v.y, w3p0r, w3p0i, T1r[0], T1i[0]);
    cmul(r2v.z, r2v.w, w3p1r, w3p1i, T1r[1], T1i[1]);
    cmul(r2v.z, r2v.w, w3p0r, w3p0i, T1r[2], T1i[2]);
    cmul(r2v.x, r2v.y, w3p1r, w3p1i, T1r[3], T1i[3]);

    // q0 RY folded into T2 (k2 = high bit of j): pairs (0,2),(1,3)
    {
        const float2 cs = *(const float2*)(lds + eb + 0*8 + 4);
        #pragma unroll
        for (int j = 0; j < 2; ++j) {
            const float lr = T2r[j], li = T2i[j], hr = T2r[j+2], hi = T2i[j+2];
            T2r[j]   = cs.x*lr - cs.y*hr;  T2i[j]   = cs.x*li - cs.y*hi;
            T2r[j+2] = cs.y*lr + cs.x*hr;  T2i[j+2] = cs.y*li + cs.x*hi;
        }
    }
    // q2 RY folded into T1 (k0 = low bit of m): pairs (0,1),(2,3)
    {
        const float2 cs = *(const float2*)(lds + eb + 2*8 + 4);
        #pragma unroll
        for (int j = 0; j < 4; j += 2) {
            const float lr = T1r[j], li = T1i[j], hr = T1r[j+1], hi = T1i[j+1];
            T1r[j]   = cs.x*lr - cs.y*hr;  T1i[j]   = cs.x*li - cs.y*hi;
            T1r[j+1] = cs.y*lr + cs.x*hr;  T1i[j+1] = cs.y*li + cs.x*hi;
        }
    }

    // ---- init amps ----
    float ar[8], ai[8];
    #pragma unroll
    for (int k = 0; k < 8; ++k)
        cmul(T2r[k >> 1], T2i[k >> 1], T1r[k & 3], T1i[k & 3], ar[k], ai[k]);

    // ---- remaining RY gates ----
    // q1: k1 (straddles trees) on full amps
    {
        const float2 cs = *(const float2*)(lds + eb + 1*8 + 4);
        #pragma unroll
        for (int k0 = 0; k0 < 8; ++k0) {
            if (k0 & 2) continue;
            const int k1 = k0 | 2;
            const float lr = ar[k0], li = ai[k0], hr = ar[k1], hi = ai[k1];
            ar[k0] = cs.x*lr - cs.y*hr;  ai[k0] = cs.x*li - cs.y*hi;
            ar[k1] = cs.y*lr + cs.x*hr;  ai[k1] = cs.y*li + cs.x*hi;
        }
    }
    // q3: lane xor16 (ds_swizzle), selector sl4
    {
        const float2 cs = *(const float2*)(lds + eb + 3*8 + 4);
        const float se = sl4 ? cs.y : -cs.y;
        #pragma unroll
        for (int k = 0; k < 8; ++k) {
            const float pr = swz<0x401F>(ar[k]);
            const float pi = swz<0x401F>(ai[k]);
            ar[k] = cs.x*ar[k] + se*pr;
            ai[k] = cs.x*ai[k] + se*pi;
        }
    }
    // q4: xor8 (row_ror:8), selector sl3
    {
        const float2 cs = *(const float2*)(lds + eb + 4*8 + 4);
        const float se = sl3 ? cs.y : -cs.y;
        #pragma unroll
        for (int k = 0; k < 8; ++k) {
            ar[k] = cs.x*ar[k] + se*dpp_perm<0x128>(ar[k]);
            ai[k] = cs.x*ai[k] + se*dpp_perm<0x128>(ai[k]);
        }
    }
    // q5: xor7 (row_half_mirror), selector sl2
    {
        const float2 cs = *(const float2*)(lds + eb + 5*8 + 4);
        const float se = sl2 ? cs.y : -cs.y;
        #pragma unroll
        for (int k = 0; k < 8; ++k) {
            ar[k] = cs.x*ar[k] + se*dpp_perm<0x141>(ar[k]);
            ai[k] = cs.x*ai[k] + se*dpp_perm<0x141>(ai[k]);
        }
    }
    // q6: xor2 (quad), selector sl1^sl2
    {
        const float2 cs = *(const float2*)(lds + eb + 6*8 + 4);
        const float se = (sl1 ^ sl2) ? cs.y : -cs.y;
        #pragma unroll
        for (int k = 0; k < 8; ++k) {
            ar[k] = cs.x*ar[k] + se*dpp_perm<0x4E>(ar[k]);
            ai[k] = cs.x*ai[k] + se*dpp_perm<0x4E>(ai[k]);
        }
    }
    // q7: xor1 (quad), selector sl0^sl2
    {
        const float2 cs = *(const float2*)(lds + eb + 7*8 + 4);
        const float se = (sl0 ^ sl2) ? cs.y : -cs.y;
        #pragma unroll
        for (int k = 0; k < 8; ++k) {
            ar[k] = cs.x*ar[k] + se*dpp_perm<0xB1>(ar[k]);
            ai[k] = cs.x*ai[k] + se*dpp_perm<0xB1>(ai[k]);
        }
    }

    // ---- Z expectations: k-part Walsh (masks 3,6,7) ----
    float P[8];
    #pragma unroll
    for (int k = 0; k < 8; ++k) P[k] = ar[k]*ar[k] + ai[k]*ai[k];
    const float u0 = P[0]+P[1], v0 = P[0]-P[1];
    const float u1 = P[2]+P[3], v1 = P[2]-P[3];
    const float u2 = P[4]+P[5], v2 = P[4]-P[5];
    const float u3 = P[6]+P[7], v3 = P[6]-P[7];
    float V3 = v0 - v1 + v2 - v3;    // (-1)^{k1+k0}
    float V6 = u0 - u1 - u2 + u3;    // (-1)^{k2+k1}
    float V7 = v0 - v1 - v2 + v3;    // (-1)^{k2+k1+k0}

    // ---- FWHT over 5 lane bits ----
    {
        const float g1 = (sl & 1) ? -1.f : 1.f;
        V3 = fmaf(g1, V3, dpp_perm<0xB1>(V3));
        V6 = fmaf(g1, V6, dpp_perm<0xB1>(V6));
        V7 = fmaf(g1, V7, dpp_perm<0xB1>(V7));
        const float g2 = (sl & 2) ? -1.f : 1.f;
        V3 = fmaf(g2, V3, dpp_perm<0x4E>(V3));
        V6 = fmaf(g2, V6, dpp_perm<0x4E>(V6));
        V7 = fmaf(g2, V7, dpp_perm<0x4E>(V7));
        const float g4 = (sl & 4) ? -1.f : 1.f;
        V3 = fmaf(g4, V3, swz<0x101F>(V3));
        V6 = fmaf(g4, V6, swz<0x101F>(V6));
        V7 = fmaf(g4, V7, swz<0x101F>(V7));
        const float g8 = (sl & 8) ? -1.f : 1.f;
        V3 = fmaf(g8, V3, dpp_perm<0x128>(V3));
        V6 = fmaf(g8, V6, dpp_perm<0x128>(V6));
        V7 = fmaf(g8, V7, dpp_perm<0x128>(V7));
        const float g16 = (sl & 16) ? -1.f : 1.f;
        V3 = fmaf(g16, V3, swz<0x401F>(V3));
        V6 = fmaf(g16, V6, swz<0x401F>(V6));
        V7 = fmaf(g16, V7, swz<0x401F>(V7));
    }

    // ---- gather per-qubit results, tanh, store ----
    // q0: V3@31  q1: V6@0  q2: V7@0  q3: V7@16  q4: V7@24  q5: V7@28
    // q6: V7@26  q7: V7@31
    const int idx7 = (sl == 3) ? 16 : (sl == 4) ? 24 : (sl == 5) ? 28
                   : (sl == 6) ? 26 : (sl == 7) ? 31 : 0;
    const float B3 = swz<0x3E0>(V3);                 // bcast lane31 of half
    const float B6 = swz<0x000>(V6);                 // bcast lane0 of half
    const float B7 = __shfl(V7, gb + idx7, 64);
    const float rsel = (sl == 0) ? B3 : (sl == 1) ? B6 : B7;
    const float h = fast_tanh(rsel);
    if (sl < 8) {
        const size_t obase = (size_t)e * 8;
        out[obase + sl] = h;
        out[(size_t)B * 8 + obase + sl] = h;
    }
}

extern "C" void kernel_launch(void* const* d_in, const int* in_sizes, int n_in,
                              void* d_out, int out_size, void* d_ws, size_t ws_size,
                              hipStream_t stream)
{
    const float* inputs = (const float*)d_in[0];   // (B, 8) fp32
    const float* hidden = (const float*)d_in[1];   // (B, 2, 1, 8, 3) fp32
    float* out = (float*)d_out;                    // (2, B, 8) fp32 (tuple (h,h))
    const int B = in_sizes[0] / 8;                 // 16384
    const int blocks = (B + 7) / 8;                // 32 lanes per element
    hipLaunchKernelGGL(qcirc_kernel, dim3(blocks), dim3(256), 0, stream,
                       inputs, hidden, out, B);
}